// Round 1
// baseline (753.563 us; speedup 1.0000x reference)
//
#include <hip/hip_runtime.h>
#include <math.h>

#define N_NODES 50000
#define N_EDGES 800000
#define EP      (N_EDGES + N_NODES)   // edges incl. self loops
#define IN_CH   128
#define HIDC    32
#define HEADS   4
#define OUTC    10
#define NGRAPH  64
#define NEG_SLOPE 0.2f

__device__ __forceinline__ float lrelu(float x) { return x > 0.f ? x : NEG_SLOPE * x; }
__device__ __forceinline__ float eluf(float x)  { return x > 0.f ? x : __expf(x) - 1.f; }

// ---------------- init ----------------
__global__ void k_init(int* __restrict__ indeg, float* __restrict__ gsum, int* __restrict__ gcnt) {
    int i = blockIdx.x * 256 + threadIdx.x;
    if (i < N_NODES) indeg[i] = 1;              // self loop
    if (i < NGRAPH * HIDC) gsum[i] = 0.f;
    if (i < NGRAPH) gcnt[i] = 0;
}

// ---------------- CSR build ----------------
__global__ void k_count(const int* __restrict__ dst, int* __restrict__ indeg) {
    int e = blockIdx.x * 256 + threadIdx.x;
    if (e < N_EDGES) atomicAdd(&indeg[dst[e]], 1);
}

__global__ void k_scan1(const int* __restrict__ indeg, int* __restrict__ incl, int* __restrict__ bsum) {
    __shared__ int s[256];
    int t = threadIdx.x;
    int i = blockIdx.x * 256 + t;
    int v = (i < N_NODES) ? indeg[i] : 0;
    s[t] = v; __syncthreads();
    for (int off = 1; off < 256; off <<= 1) {
        int x = (t >= off) ? s[t - off] : 0;
        __syncthreads();
        s[t] += x;
        __syncthreads();
    }
    if (i < N_NODES) incl[i] = s[t];
    if (t == 255) bsum[blockIdx.x] = s[255];
}

__global__ void k_scan2(int* __restrict__ bsum, int nb) {
    __shared__ int s[256];
    int t = threadIdx.x;
    int v = (t < nb) ? bsum[t] : 0;
    s[t] = v; __syncthreads();
    for (int off = 1; off < 256; off <<= 1) {
        int x = (t >= off) ? s[t - off] : 0;
        __syncthreads();
        s[t] += x;
        __syncthreads();
    }
    if (t < nb) bsum[t] = s[t] - v;   // exclusive
}

__global__ void k_scan3(const int* __restrict__ indeg, int* __restrict__ csr,
                        const int* __restrict__ boff, int* __restrict__ pos) {
    int i = blockIdx.x * 256 + threadIdx.x;
    if (i >= N_NODES) return;
    int inc = csr[i] + boff[i >> 8];
    int ex = inc - indeg[i];
    csr[i] = ex;
    pos[i] = ex;
    if (i == N_NODES - 1) csr[N_NODES] = inc;
}

__global__ void k_scatter(const int* __restrict__ dst, int* __restrict__ pos, int* __restrict__ eid) {
    int t = blockIdx.x * 256 + threadIdx.x;
    if (t < N_EDGES) {
        int d = dst[t];
        int p = atomicAdd(&pos[d], 1);
        eid[p] = t;
    } else if (t < EP) {
        int n = t - N_EDGES;
        int p = atomicAdd(&pos[n], 1);
        eid[p] = t;                   // value E+n marks self loop of node n
    }
}

// ---------------- GEMM1: h1 = x @ W1  (128 -> 128) ----------------
__global__ __launch_bounds__(256) void k_gemm1(const float* __restrict__ x,
                                               const float* __restrict__ W,
                                               float* __restrict__ h) {
    __shared__ float Ws[128 * 128];   // 64 KB
    __shared__ float Xs[32 * 128];    // 16 KB
    int t = threadIdx.x;
    int row0 = blockIdx.x * 32;
    for (int idx = t * 4; idx < 128 * 128; idx += 1024)
        *(float4*)&Ws[idx] = *(const float4*)&W[idx];
    for (int idx = t * 4; idx < 32 * 128; idx += 1024) {
        int gr = row0 + (idx >> 7);
        float4 v = {0.f, 0.f, 0.f, 0.f};
        if (gr < N_NODES) v = *(const float4*)&x[gr * 128 + (idx & 127)];
        *(float4*)&Xs[idx] = v;
    }
    __syncthreads();
    int rp = t >> 4;              // 0..15
    int jg = (t & 15) * 8;        // col base
    float4 a00 = {0,0,0,0}, a01 = {0,0,0,0}, a10 = {0,0,0,0}, a11 = {0,0,0,0};
#pragma unroll 4
    for (int k = 0; k < 128; k++) {
        float xv0 = Xs[rp * 128 + k];
        float xv1 = Xs[(rp + 16) * 128 + k];
        float4 wa = *(float4*)&Ws[k * 128 + jg];
        float4 wb = *(float4*)&Ws[k * 128 + jg + 4];
        a00.x += xv0 * wa.x; a00.y += xv0 * wa.y; a00.z += xv0 * wa.z; a00.w += xv0 * wa.w;
        a01.x += xv0 * wb.x; a01.y += xv0 * wb.y; a01.z += xv0 * wb.z; a01.w += xv0 * wb.w;
        a10.x += xv1 * wa.x; a10.y += xv1 * wa.y; a10.z += xv1 * wa.z; a10.w += xv1 * wa.w;
        a11.x += xv1 * wb.x; a11.y += xv1 * wb.y; a11.z += xv1 * wb.z; a11.w += xv1 * wb.w;
    }
    int r0 = row0 + rp, r1 = row0 + rp + 16;
    if (r0 < N_NODES) {
        *(float4*)&h[r0 * 128 + jg] = a00;
        *(float4*)&h[r0 * 128 + jg + 4] = a01;
    }
    if (r1 < N_NODES) {
        *(float4*)&h[r1 * 128 + jg] = a10;
        *(float4*)&h[r1 * 128 + jg + 4] = a11;
    }
}

// ---------------- attention logits conv1 ----------------
__global__ __launch_bounds__(256) void k_al1(const float* __restrict__ h,
                                             const float* __restrict__ asrc, const float* __restrict__ adst,
                                             float* __restrict__ als, float* __restrict__ ald) {
    int l = threadIdx.x & 63;
    int n = blockIdx.x * 4 + (threadIdx.x >> 6);
    if (n >= N_NODES) return;
    float h0 = h[n * 128 + l], h1v = h[n * 128 + 64 + l];
    float ps0 = h0 * asrc[l], ps1 = h1v * asrc[64 + l];
    float pd0 = h0 * adst[l], pd1 = h1v * adst[64 + l];
    for (int off = 1; off < 32; off <<= 1) {
        ps0 += __shfl_xor(ps0, off); ps1 += __shfl_xor(ps1, off);
        pd0 += __shfl_xor(pd0, off); pd1 += __shfl_xor(pd1, off);
    }
    if (l == 0)  { als[n*4+0] = ps0; als[n*4+2] = ps1; ald[n*4+0] = pd0; ald[n*4+2] = pd1; }
    if (l == 32) { als[n*4+1] = ps0; als[n*4+3] = ps1; ald[n*4+1] = pd0; ald[n*4+3] = pd1; }
}

// ---------------- aggregation conv1 (wave per node) ----------------
__global__ __launch_bounds__(256) void k_agg1(const float* __restrict__ h,
                                              const int* __restrict__ csr, const int* __restrict__ eid,
                                              const int* __restrict__ srcA,
                                              const float* __restrict__ als, const float* __restrict__ ald,
                                              const float* __restrict__ b1, float* __restrict__ out) {
    int l = threadIdx.x & 63;
    int n = blockIdx.x * 4 + (threadIdx.x >> 6);
    if (n >= N_NODES) return;
    int start = csr[n], end = csr[n + 1];
    float ad0 = ald[n*4+0], ad1 = ald[n*4+1], ad2 = ald[n*4+2], ad3 = ald[n*4+3];
    float m0 = -INFINITY, m1 = -INFINITY, m2 = -INFINITY, m3 = -INFINITY;
    for (int i = start + l; i < end; i += 64) {
        int e = eid[i]; int s = (e < N_EDGES) ? srcA[e] : (e - N_EDGES);
        float4 as = *(const float4*)&als[s * 4];
        m0 = fmaxf(m0, lrelu(as.x + ad0));
        m1 = fmaxf(m1, lrelu(as.y + ad1));
        m2 = fmaxf(m2, lrelu(as.z + ad2));
        m3 = fmaxf(m3, lrelu(as.w + ad3));
    }
    for (int off = 1; off < 64; off <<= 1) {
        m0 = fmaxf(m0, __shfl_xor(m0, off));
        m1 = fmaxf(m1, __shfl_xor(m1, off));
        m2 = fmaxf(m2, __shfl_xor(m2, off));
        m3 = fmaxf(m3, __shfl_xor(m3, off));
    }
    float s0 = 0, s1 = 0, s2 = 0, s3 = 0;
    for (int i = start + l; i < end; i += 64) {
        int e = eid[i]; int s = (e < N_EDGES) ? srcA[e] : (e - N_EDGES);
        float4 as = *(const float4*)&als[s * 4];
        s0 += __expf(lrelu(as.x + ad0) - m0);
        s1 += __expf(lrelu(as.y + ad1) - m1);
        s2 += __expf(lrelu(as.z + ad2) - m2);
        s3 += __expf(lrelu(as.w + ad3) - m3);
    }
    for (int off = 1; off < 64; off <<= 1) {
        s0 += __shfl_xor(s0, off); s1 += __shfl_xor(s1, off);
        s2 += __shfl_xor(s2, off); s3 += __shfl_xor(s3, off);
    }
    float inv0 = 1.f / s0, inv1 = 1.f / s1, inv2 = 1.f / s2, inv3 = 1.f / s3;
    bool lo = l < 32;
    int c0 = l, c1 = l + 64;
    float mh0 = lo ? m0 : m1, mh1 = lo ? m2 : m3;
    float ih0 = lo ? inv0 : inv1, ih1 = lo ? inv2 : inv3;
    float adh0 = lo ? ad0 : ad1, adh1 = lo ? ad2 : ad3;
    int ho0 = lo ? 0 : 1, ho1 = lo ? 2 : 3;
    float acc0 = 0.f, acc1 = 0.f;
    for (int i = start; i < end; i++) {
        int e = eid[i]; int s = (e < N_EDGES) ? srcA[e] : (e - N_EDGES);
        float as0 = als[s * 4 + ho0], as1 = als[s * 4 + ho1];
        float a0 = __expf(lrelu(as0 + adh0) - mh0) * ih0;
        float a1 = __expf(lrelu(as1 + adh1) - mh1) * ih1;
        acc0 += h[s * 128 + c0] * a0;
        acc1 += h[s * 128 + c1] * a1;
    }
    out[n * 128 + c0] = eluf(acc0 + b1[c0]);
    out[n * 128 + c1] = eluf(acc1 + b1[c1]);
}

// ---------------- GEMM2: h2 = o1 @ W2  (128 -> 32) ----------------
__global__ __launch_bounds__(256) void k_gemm2(const float* __restrict__ x,
                                               const float* __restrict__ W,
                                               float* __restrict__ h2) {
    __shared__ float Ws[128 * 32];    // 16 KB
    __shared__ float Xs[32 * 128];    // 16 KB
    int t = threadIdx.x;
    int row0 = blockIdx.x * 32;
    for (int idx = t * 4; idx < 128 * 32; idx += 1024)
        *(float4*)&Ws[idx] = *(const float4*)&W[idx];
    for (int idx = t * 4; idx < 32 * 128; idx += 1024) {
        int gr = row0 + (idx >> 7);
        float4 v = {0.f, 0.f, 0.f, 0.f};
        if (gr < N_NODES) v = *(const float4*)&x[gr * 128 + (idx & 127)];
        *(float4*)&Xs[idx] = v;
    }
    __syncthreads();
    int r = t >> 3;
    int jg = (t & 7) * 4;
    float a0 = 0, a1 = 0, a2 = 0, a3 = 0;
#pragma unroll 4
    for (int k = 0; k < 128; k++) {
        float xv = Xs[r * 128 + k];
        float4 w = *(float4*)&Ws[k * 32 + jg];
        a0 += xv * w.x; a1 += xv * w.y; a2 += xv * w.z; a3 += xv * w.w;
    }
    int gr = row0 + r;
    if (gr < N_NODES) {
        float4 o = {a0, a1, a2, a3};
        *(float4*)&h2[gr * 32 + jg] = o;
    }
}

// ---------------- attention logits conv2 ----------------
__global__ __launch_bounds__(256) void k_al2(const float* __restrict__ h2,
                                             const float* __restrict__ asrc, const float* __restrict__ adst,
                                             float* __restrict__ als, float* __restrict__ ald) {
    int t = threadIdx.x;
    int c = t & 31;
    int n = blockIdx.x * 8 + (t >> 5);
    if (n >= N_NODES) return;
    float hv = h2[n * 32 + c];
    float ps = hv * asrc[c], pd = hv * adst[c];
    for (int off = 1; off < 32; off <<= 1) {
        ps += __shfl_xor(ps, off);
        pd += __shfl_xor(pd, off);
    }
    if (c == 0) { als[n] = ps; ald[n] = pd; }
}

// ---------------- aggregation conv2 (wave per node) ----------------
__global__ __launch_bounds__(256) void k_agg2(const float* __restrict__ h2,
                                              const int* __restrict__ csr, const int* __restrict__ eid,
                                              const int* __restrict__ srcA,
                                              const float* __restrict__ als, const float* __restrict__ ald,
                                              const float* __restrict__ b2, float* __restrict__ out2) {
    int l = threadIdx.x & 63;
    int n = blockIdx.x * 4 + (threadIdx.x >> 6);
    if (n >= N_NODES) return;
    int start = csr[n], end = csr[n + 1];
    float ad = ald[n];
    float m = -INFINITY;
    for (int i = start + l; i < end; i += 64) {
        int e = eid[i]; int s = (e < N_EDGES) ? srcA[e] : (e - N_EDGES);
        m = fmaxf(m, lrelu(als[s] + ad));
    }
    for (int off = 1; off < 64; off <<= 1) m = fmaxf(m, __shfl_xor(m, off));
    float sum = 0.f;
    for (int i = start + l; i < end; i += 64) {
        int e = eid[i]; int s = (e < N_EDGES) ? srcA[e] : (e - N_EDGES);
        sum += __expf(lrelu(als[s] + ad) - m);
    }
    for (int off = 1; off < 64; off <<= 1) sum += __shfl_xor(sum, off);
    float inv = 1.f / sum;
    int hi = l >> 5, c = l & 31;
    float acc = 0.f;
    for (int i = start + hi; i < end; i += 2) {
        int e = eid[i]; int s = (e < N_EDGES) ? srcA[e] : (e - N_EDGES);
        float a = __expf(lrelu(als[s] + ad) - m) * inv;
        acc += h2[s * 32 + c] * a;
    }
    acc += __shfl_xor(acc, 32);
    if (l < 32) out2[n * 32 + c] = eluf(acc + b2[c]);
}

// ---------------- pooling ----------------
__global__ void k_pool(const float* __restrict__ out2, const int* __restrict__ batch,
                       float* __restrict__ gsum) {
    int i = blockIdx.x * 256 + threadIdx.x;
    if (i >= N_NODES * 32) return;
    int n = i >> 5, c = i & 31;
    atomicAdd(&gsum[batch[n] * 32 + c], out2[i]);
}

__global__ void k_cnt(const int* __restrict__ batch, int* __restrict__ gcnt) {
    int n = blockIdx.x * 256 + threadIdx.x;
    if (n < N_NODES) atomicAdd(&gcnt[batch[n]], 1);
}

// ---------------- final linear ----------------
__global__ void k_final(const float* __restrict__ gsum, const int* __restrict__ gcnt,
                        const float* __restrict__ Wl, const float* __restrict__ bl,
                        float* __restrict__ out) {
    int t = threadIdx.x;
    if (t >= NGRAPH * OUTC) return;
    int g = t / OUTC, o = t % OUTC;
    float d = fmaxf((float)gcnt[g], 1.f);
    float acc = 0.f;
    for (int c = 0; c < HIDC; c++)
        acc += (gsum[g * HIDC + c] / d) * Wl[c * OUTC + o];
    out[t] = acc + bl[o];
}

extern "C" void kernel_launch(void* const* d_in, const int* in_sizes, int n_in,
                              void* d_out, int out_size, void* d_ws, size_t ws_size,
                              hipStream_t stream) {
    (void)in_sizes; (void)n_in; (void)out_size; (void)ws_size;
    const float* x    = (const float*)d_in[0];
    const int*   ei   = (const int*)d_in[1];
    const int*   srcA = ei;
    const int*   dstA = ei + N_EDGES;
    const int*   batch = (const int*)d_in[2];
    const float* W1  = (const float*)d_in[3];
    const float* a1s = (const float*)d_in[4];
    const float* a1d = (const float*)d_in[5];
    const float* b1  = (const float*)d_in[6];
    const float* W2  = (const float*)d_in[7];
    const float* a2s = (const float*)d_in[8];
    const float* a2d = (const float*)d_in[9];
    const float* b2  = (const float*)d_in[10];
    const float* Wl  = (const float*)d_in[11];
    const float* bl  = (const float*)d_in[12];
    float* out = (float*)d_out;

    char* w = (char*)d_ws;
    auto alloc = [&](size_t bytes) -> void* {
        void* p = (void*)w;
        w += (bytes + 255) & ~(size_t)255;
        return p;
    };
    float* h1   = (float*)alloc((size_t)N_NODES * 128 * 4);
    float* o1   = (float*)alloc((size_t)N_NODES * 128 * 4);
    float* als1 = (float*)alloc((size_t)N_NODES * 4 * 4);
    float* ald1 = (float*)alloc((size_t)N_NODES * 4 * 4);
    float* h2   = (float*)alloc((size_t)N_NODES * 32 * 4);
    float* o2   = (float*)alloc((size_t)N_NODES * 32 * 4);
    float* als2 = (float*)alloc((size_t)N_NODES * 4);
    float* ald2 = (float*)alloc((size_t)N_NODES * 4);
    int*   indeg = (int*)alloc((size_t)N_NODES * 4);
    int*   csr   = (int*)alloc((size_t)(N_NODES + 1) * 4);
    int*   pos   = (int*)alloc((size_t)N_NODES * 4);
    int*   eid   = (int*)alloc((size_t)EP * 4);
    int*   bsum  = (int*)alloc(256 * 4);
    float* gsum  = (float*)alloc((size_t)NGRAPH * 32 * 4);
    int*   gcnt  = (int*)alloc((size_t)NGRAPH * 4);

    int nb = (N_NODES + 255) / 256;   // 196

    k_init<<<nb, 256, 0, stream>>>(indeg, gsum, gcnt);
    k_count<<<(N_EDGES + 255) / 256, 256, 0, stream>>>(dstA, indeg);
    k_scan1<<<nb, 256, 0, stream>>>(indeg, csr, bsum);
    k_scan2<<<1, 256, 0, stream>>>(bsum, nb);
    k_scan3<<<nb, 256, 0, stream>>>(indeg, csr, bsum, pos);
    k_scatter<<<(EP + 255) / 256, 256, 0, stream>>>(dstA, pos, eid);
    k_gemm1<<<(N_NODES + 31) / 32, 256, 0, stream>>>(x, W1, h1);
    k_al1<<<(N_NODES + 3) / 4, 256, 0, stream>>>(h1, a1s, a1d, als1, ald1);
    k_agg1<<<(N_NODES + 3) / 4, 256, 0, stream>>>(h1, csr, eid, srcA, als1, ald1, b1, o1);
    k_gemm2<<<(N_NODES + 31) / 32, 256, 0, stream>>>(o1, W2, h2);
    k_al2<<<(N_NODES + 7) / 8, 256, 0, stream>>>(h2, a2s, a2d, als2, ald2);
    k_agg2<<<(N_NODES + 3) / 4, 256, 0, stream>>>(h2, csr, eid, srcA, als2, ald2, b2, o2);
    k_pool<<<(N_NODES * 32 + 255) / 256, 256, 0, stream>>>(o2, batch, gsum);
    k_cnt<<<nb, 256, 0, stream>>>(batch, gcnt);
    k_final<<<1, 640, 0, stream>>>(gsum, gcnt, Wl, bl, out);
}

// Round 2
// 472.134 us; speedup vs baseline: 1.5961x; 1.5961x over previous
//
#include <hip/hip_runtime.h>
#include <math.h>

#define N_NODES 50000
#define N_EDGES 800000
#define EP      (N_EDGES + N_NODES)   // edges incl. self loops
#define IN_CH   128
#define HIDC    32
#define HEADS   4
#define OUTC    10
#define NGRAPH  64
#define NEG_SLOPE 0.2f

__device__ __forceinline__ float lrelu(float x) { return x > 0.f ? x : NEG_SLOPE * x; }
__device__ __forceinline__ float eluf(float x)  { return x > 0.f ? x : __expf(x) - 1.f; }

// ---------------- init ----------------
__global__ void k_init(int* __restrict__ indeg) {
    int i = blockIdx.x * 256 + threadIdx.x;
    if (i < N_NODES) indeg[i] = 1;              // self loop
}

// ---------------- CSR build ----------------
__global__ void k_count(const int* __restrict__ dst, int* __restrict__ indeg) {
    int e = blockIdx.x * 256 + threadIdx.x;
    if (e < N_EDGES) atomicAdd(&indeg[dst[e]], 1);
}

__global__ void k_scan1(const int* __restrict__ indeg, int* __restrict__ incl, int* __restrict__ bsum) {
    __shared__ int s[256];
    int t = threadIdx.x;
    int i = blockIdx.x * 256 + t;
    int v = (i < N_NODES) ? indeg[i] : 0;
    s[t] = v; __syncthreads();
    for (int off = 1; off < 256; off <<= 1) {
        int x = (t >= off) ? s[t - off] : 0;
        __syncthreads();
        s[t] += x;
        __syncthreads();
    }
    if (i < N_NODES) incl[i] = s[t];
    if (t == 255) bsum[blockIdx.x] = s[255];
}

__global__ void k_scan2(int* __restrict__ bsum, int nb) {
    __shared__ int s[256];
    int t = threadIdx.x;
    int v = (t < nb) ? bsum[t] : 0;
    s[t] = v; __syncthreads();
    for (int off = 1; off < 256; off <<= 1) {
        int x = (t >= off) ? s[t - off] : 0;
        __syncthreads();
        s[t] += x;
        __syncthreads();
    }
    if (t < nb) bsum[t] = s[t] - v;   // exclusive
}

__global__ void k_scan3(const int* __restrict__ indeg, int* __restrict__ csr,
                        const int* __restrict__ boff, int* __restrict__ pos) {
    int i = blockIdx.x * 256 + threadIdx.x;
    if (i >= N_NODES) return;
    int inc = csr[i] + boff[i >> 8];
    int ex = inc - indeg[i];
    csr[i] = ex;
    pos[i] = ex;
    if (i == N_NODES - 1) csr[N_NODES] = inc;
}

__global__ void k_scatter(const int* __restrict__ dst, int* __restrict__ pos, int* __restrict__ eid) {
    int t = blockIdx.x * 256 + threadIdx.x;
    if (t < N_EDGES) {
        int d = dst[t];
        int p = atomicAdd(&pos[d], 1);
        eid[p] = t;
    } else if (t < EP) {
        int n = t - N_EDGES;
        int p = atomicAdd(&pos[n], 1);
        eid[p] = t;                   // value E+n marks self loop of node n
    }
}

// ---------------- graph boundaries (batch is sorted) ----------------
__global__ void k_bounds(const int* __restrict__ batch, int* __restrict__ goff) {
    int g = threadIdx.x;
    if (g > NGRAPH) return;
    int lo = 0, hi = N_NODES;
    while (lo < hi) {
        int mid = (lo + hi) >> 1;
        if (batch[mid] < g) lo = mid + 1; else hi = mid;
    }
    goff[g] = lo;
}

// ---------------- GEMM1: h1 = x @ W1  (128 -> 128) ----------------
__global__ __launch_bounds__(256) void k_gemm1(const float* __restrict__ x,
                                               const float* __restrict__ W,
                                               float* __restrict__ h) {
    __shared__ float Ws[128 * 128];   // 64 KB
    __shared__ float Xs[32 * 128];    // 16 KB
    int t = threadIdx.x;
    int row0 = blockIdx.x * 32;
    for (int idx = t * 4; idx < 128 * 128; idx += 1024)
        *(float4*)&Ws[idx] = *(const float4*)&W[idx];
    for (int idx = t * 4; idx < 32 * 128; idx += 1024) {
        int gr = row0 + (idx >> 7);
        float4 v = {0.f, 0.f, 0.f, 0.f};
        if (gr < N_NODES) v = *(const float4*)&x[gr * 128 + (idx & 127)];
        *(float4*)&Xs[idx] = v;
    }
    __syncthreads();
    int rp = t >> 4;              // 0..15
    int jg = (t & 15) * 8;        // col base
    float4 a00 = {0,0,0,0}, a01 = {0,0,0,0}, a10 = {0,0,0,0}, a11 = {0,0,0,0};
#pragma unroll 4
    for (int k = 0; k < 128; k++) {
        float xv0 = Xs[rp * 128 + k];
        float xv1 = Xs[(rp + 16) * 128 + k];
        float4 wa = *(float4*)&Ws[k * 128 + jg];
        float4 wb = *(float4*)&Ws[k * 128 + jg + 4];
        a00.x += xv0 * wa.x; a00.y += xv0 * wa.y; a00.z += xv0 * wa.z; a00.w += xv0 * wa.w;
        a01.x += xv0 * wb.x; a01.y += xv0 * wb.y; a01.z += xv0 * wb.z; a01.w += xv0 * wb.w;
        a10.x += xv1 * wa.x; a10.y += xv1 * wa.y; a10.z += xv1 * wa.z; a10.w += xv1 * wa.w;
        a11.x += xv1 * wb.x; a11.y += xv1 * wb.y; a11.z += xv1 * wb.z; a11.w += xv1 * wb.w;
    }
    int r0 = row0 + rp, r1 = row0 + rp + 16;
    if (r0 < N_NODES) {
        *(float4*)&h[r0 * 128 + jg] = a00;
        *(float4*)&h[r0 * 128 + jg + 4] = a01;
    }
    if (r1 < N_NODES) {
        *(float4*)&h[r1 * 128 + jg] = a10;
        *(float4*)&h[r1 * 128 + jg + 4] = a11;
    }
}

// ---------------- attention logits conv1 ----------------
__global__ __launch_bounds__(256) void k_al1(const float* __restrict__ h,
                                             const float* __restrict__ asrc, const float* __restrict__ adst,
                                             float* __restrict__ als, float* __restrict__ ald) {
    int l = threadIdx.x & 63;
    int n = blockIdx.x * 4 + (threadIdx.x >> 6);
    if (n >= N_NODES) return;
    float h0 = h[n * 128 + l], h1v = h[n * 128 + 64 + l];
    float ps0 = h0 * asrc[l], ps1 = h1v * asrc[64 + l];
    float pd0 = h0 * adst[l], pd1 = h1v * adst[64 + l];
    for (int off = 1; off < 32; off <<= 1) {
        ps0 += __shfl_xor(ps0, off); ps1 += __shfl_xor(ps1, off);
        pd0 += __shfl_xor(pd0, off); pd1 += __shfl_xor(pd1, off);
    }
    if (l == 0)  { als[n*4+0] = ps0; als[n*4+2] = ps1; ald[n*4+0] = pd0; ald[n*4+2] = pd1; }
    if (l == 32) { als[n*4+1] = ps0; als[n*4+3] = ps1; ald[n*4+1] = pd0; ald[n*4+3] = pd1; }
}

// ---------------- aggregation conv1 (wave per node) ----------------
__global__ __launch_bounds__(256) void k_agg1(const float* __restrict__ h,
                                              const int* __restrict__ csr, const int* __restrict__ eid,
                                              const int* __restrict__ srcA,
                                              const float* __restrict__ als, const float* __restrict__ ald,
                                              const float* __restrict__ b1, float* __restrict__ out) {
    int l = threadIdx.x & 63;
    int n = blockIdx.x * 4 + (threadIdx.x >> 6);
    if (n >= N_NODES) return;
    int start = csr[n], end = csr[n + 1];
    float ad0 = ald[n*4+0], ad1 = ald[n*4+1], ad2 = ald[n*4+2], ad3 = ald[n*4+3];
    float m0 = -INFINITY, m1 = -INFINITY, m2 = -INFINITY, m3 = -INFINITY;
    for (int i = start + l; i < end; i += 64) {
        int e = eid[i]; int s = (e < N_EDGES) ? srcA[e] : (e - N_EDGES);
        float4 as = *(const float4*)&als[s * 4];
        m0 = fmaxf(m0, lrelu(as.x + ad0));
        m1 = fmaxf(m1, lrelu(as.y + ad1));
        m2 = fmaxf(m2, lrelu(as.z + ad2));
        m3 = fmaxf(m3, lrelu(as.w + ad3));
    }
    for (int off = 1; off < 64; off <<= 1) {
        m0 = fmaxf(m0, __shfl_xor(m0, off));
        m1 = fmaxf(m1, __shfl_xor(m1, off));
        m2 = fmaxf(m2, __shfl_xor(m2, off));
        m3 = fmaxf(m3, __shfl_xor(m3, off));
    }
    float s0 = 0, s1 = 0, s2 = 0, s3 = 0;
    for (int i = start + l; i < end; i += 64) {
        int e = eid[i]; int s = (e < N_EDGES) ? srcA[e] : (e - N_EDGES);
        float4 as = *(const float4*)&als[s * 4];
        s0 += __expf(lrelu(as.x + ad0) - m0);
        s1 += __expf(lrelu(as.y + ad1) - m1);
        s2 += __expf(lrelu(as.z + ad2) - m2);
        s3 += __expf(lrelu(as.w + ad3) - m3);
    }
    for (int off = 1; off < 64; off <<= 1) {
        s0 += __shfl_xor(s0, off); s1 += __shfl_xor(s1, off);
        s2 += __shfl_xor(s2, off); s3 += __shfl_xor(s3, off);
    }
    float inv0 = 1.f / s0, inv1 = 1.f / s1, inv2 = 1.f / s2, inv3 = 1.f / s3;
    bool lo = l < 32;
    int c0 = l, c1 = l + 64;
    float mh0 = lo ? m0 : m1, mh1 = lo ? m2 : m3;
    float ih0 = lo ? inv0 : inv1, ih1 = lo ? inv2 : inv3;
    float adh0 = lo ? ad0 : ad1, adh1 = lo ? ad2 : ad3;
    int ho0 = lo ? 0 : 1, ho1 = lo ? 2 : 3;
    float acc0 = 0.f, acc1 = 0.f;
    for (int i = start; i < end; i++) {
        int e = eid[i]; int s = (e < N_EDGES) ? srcA[e] : (e - N_EDGES);
        float as0 = als[s * 4 + ho0], as1 = als[s * 4 + ho1];
        float a0 = __expf(lrelu(as0 + adh0) - mh0) * ih0;
        float a1 = __expf(lrelu(as1 + adh1) - mh1) * ih1;
        acc0 += h[s * 128 + c0] * a0;
        acc1 += h[s * 128 + c1] * a1;
    }
    out[n * 128 + c0] = eluf(acc0 + b1[c0]);
    out[n * 128 + c1] = eluf(acc1 + b1[c1]);
}

// ---------------- GEMM2: h2 = o1 @ W2  (128 -> 32) ----------------
__global__ __launch_bounds__(256) void k_gemm2(const float* __restrict__ x,
                                               const float* __restrict__ W,
                                               float* __restrict__ h2) {
    __shared__ float Ws[128 * 32];    // 16 KB
    __shared__ float Xs[32 * 128];    // 16 KB
    int t = threadIdx.x;
    int row0 = blockIdx.x * 32;
    for (int idx = t * 4; idx < 128 * 32; idx += 1024)
        *(float4*)&Ws[idx] = *(const float4*)&W[idx];
    for (int idx = t * 4; idx < 32 * 128; idx += 1024) {
        int gr = row0 + (idx >> 7);
        float4 v = {0.f, 0.f, 0.f, 0.f};
        if (gr < N_NODES) v = *(const float4*)&x[gr * 128 + (idx & 127)];
        *(float4*)&Xs[idx] = v;
    }
    __syncthreads();
    int r = t >> 3;
    int jg = (t & 7) * 4;
    float a0 = 0, a1 = 0, a2 = 0, a3 = 0;
#pragma unroll 4
    for (int k = 0; k < 128; k++) {
        float xv = Xs[r * 128 + k];
        float4 w = *(float4*)&Ws[k * 32 + jg];
        a0 += xv * w.x; a1 += xv * w.y; a2 += xv * w.z; a3 += xv * w.w;
    }
    int gr = row0 + r;
    if (gr < N_NODES) {
        float4 o = {a0, a1, a2, a3};
        *(float4*)&h2[gr * 32 + jg] = o;
    }
}

// ---------------- attention logits conv2 ----------------
__global__ __launch_bounds__(256) void k_al2(const float* __restrict__ h2,
                                             const float* __restrict__ asrc, const float* __restrict__ adst,
                                             float* __restrict__ als, float* __restrict__ ald) {
    int t = threadIdx.x;
    int c = t & 31;
    int n = blockIdx.x * 8 + (t >> 5);
    if (n >= N_NODES) return;
    float hv = h2[n * 32 + c];
    float ps = hv * asrc[c], pd = hv * adst[c];
    for (int off = 1; off < 32; off <<= 1) {
        ps += __shfl_xor(ps, off);
        pd += __shfl_xor(pd, off);
    }
    if (c == 0) { als[n] = ps; ald[n] = pd; }
}

// ---------------- aggregation conv2 (wave per node) ----------------
__global__ __launch_bounds__(256) void k_agg2(const float* __restrict__ h2,
                                              const int* __restrict__ csr, const int* __restrict__ eid,
                                              const int* __restrict__ srcA,
                                              const float* __restrict__ als, const float* __restrict__ ald,
                                              const float* __restrict__ b2, float* __restrict__ out2) {
    int l = threadIdx.x & 63;
    int n = blockIdx.x * 4 + (threadIdx.x >> 6);
    if (n >= N_NODES) return;
    int start = csr[n], end = csr[n + 1];
    float ad = ald[n];
    float m = -INFINITY;
    for (int i = start + l; i < end; i += 64) {
        int e = eid[i]; int s = (e < N_EDGES) ? srcA[e] : (e - N_EDGES);
        m = fmaxf(m, lrelu(als[s] + ad));
    }
    for (int off = 1; off < 64; off <<= 1) m = fmaxf(m, __shfl_xor(m, off));
    float sum = 0.f;
    for (int i = start + l; i < end; i += 64) {
        int e = eid[i]; int s = (e < N_EDGES) ? srcA[e] : (e - N_EDGES);
        sum += __expf(lrelu(als[s] + ad) - m);
    }
    for (int off = 1; off < 64; off <<= 1) sum += __shfl_xor(sum, off);
    float inv = 1.f / sum;
    int hi = l >> 5, c = l & 31;
    float acc = 0.f;
    for (int i = start + hi; i < end; i += 2) {
        int e = eid[i]; int s = (e < N_EDGES) ? srcA[e] : (e - N_EDGES);
        float a = __expf(lrelu(als[s] + ad) - m) * inv;
        acc += h2[s * 32 + c] * a;
    }
    acc += __shfl_xor(acc, 32);
    if (l < 32) out2[n * 32 + c] = eluf(acc + b2[c]);
}

// ---------------- fused pool + final linear (batch sorted, no atomics) ----------------
__global__ __launch_bounds__(256) void k_poolfinal(const float* __restrict__ out2,
                                                   const int* __restrict__ goff,
                                                   const float* __restrict__ Wl,
                                                   const float* __restrict__ bl,
                                                   float* __restrict__ out) {
    __shared__ float red[4][32];
    __shared__ float pooled[32];
    int g = blockIdx.x;
    int s = goff[g], e = goff[g + 1];
    int t = threadIdx.x;
    int c = t & 31, r = t >> 5;           // 8 rows per sweep
    float acc = 0.f;
    for (int i = s + r; i < e; i += 8)
        acc += out2[i * 32 + c];
    acc += __shfl_xor(acc, 32);           // combine 2 rows within wave
    if ((t & 63) < 32) red[t >> 6][c] = acc;
    __syncthreads();
    if (t < 32) {
        float v = red[0][t] + red[1][t] + red[2][t] + red[3][t];
        float cnt = fmaxf((float)(e - s), 1.f);
        pooled[t] = v / cnt;
    }
    __syncthreads();
    if (t < OUTC) {
        float a = 0.f;
        for (int cc = 0; cc < HIDC; cc++)
            a += pooled[cc] * Wl[cc * OUTC + t];
        out[g * OUTC + t] = a + bl[t];
    }
}

extern "C" void kernel_launch(void* const* d_in, const int* in_sizes, int n_in,
                              void* d_out, int out_size, void* d_ws, size_t ws_size,
                              hipStream_t stream) {
    (void)in_sizes; (void)n_in; (void)out_size; (void)ws_size;
    const float* x    = (const float*)d_in[0];
    const int*   ei   = (const int*)d_in[1];
    const int*   srcA = ei;
    const int*   dstA = ei + N_EDGES;
    const int*   batch = (const int*)d_in[2];
    const float* W1  = (const float*)d_in[3];
    const float* a1s = (const float*)d_in[4];
    const float* a1d = (const float*)d_in[5];
    const float* b1  = (const float*)d_in[6];
    const float* W2  = (const float*)d_in[7];
    const float* a2s = (const float*)d_in[8];
    const float* a2d = (const float*)d_in[9];
    const float* b2  = (const float*)d_in[10];
    const float* Wl  = (const float*)d_in[11];
    const float* bl  = (const float*)d_in[12];
    float* out = (float*)d_out;

    char* w = (char*)d_ws;
    auto alloc = [&](size_t bytes) -> void* {
        void* p = (void*)w;
        w += (bytes + 255) & ~(size_t)255;
        return p;
    };
    float* h1   = (float*)alloc((size_t)N_NODES * 128 * 4);
    float* o1   = (float*)alloc((size_t)N_NODES * 128 * 4);
    float* als1 = (float*)alloc((size_t)N_NODES * 4 * 4);
    float* ald1 = (float*)alloc((size_t)N_NODES * 4 * 4);
    float* h2   = (float*)alloc((size_t)N_NODES * 32 * 4);
    float* o2   = (float*)alloc((size_t)N_NODES * 32 * 4);
    float* als2 = (float*)alloc((size_t)N_NODES * 4);
    float* ald2 = (float*)alloc((size_t)N_NODES * 4);
    int*   indeg = (int*)alloc((size_t)N_NODES * 4);
    int*   csr   = (int*)alloc((size_t)(N_NODES + 1) * 4);
    int*   pos   = (int*)alloc((size_t)N_NODES * 4);
    int*   eid   = (int*)alloc((size_t)EP * 4);
    int*   bsum  = (int*)alloc(256 * 4);
    int*   goff  = (int*)alloc((size_t)(NGRAPH + 1) * 4);

    int nb = (N_NODES + 255) / 256;   // 196

    k_init<<<nb, 256, 0, stream>>>(indeg);
    k_count<<<(N_EDGES + 255) / 256, 256, 0, stream>>>(dstA, indeg);
    k_scan1<<<nb, 256, 0, stream>>>(indeg, csr, bsum);
    k_scan2<<<1, 256, 0, stream>>>(bsum, nb);
    k_scan3<<<nb, 256, 0, stream>>>(indeg, csr, bsum, pos);
    k_scatter<<<(EP + 255) / 256, 256, 0, stream>>>(dstA, pos, eid);
    k_bounds<<<1, 128, 0, stream>>>(batch, goff);
    k_gemm1<<<(N_NODES + 31) / 32, 256, 0, stream>>>(x, W1, h1);
    k_al1<<<(N_NODES + 3) / 4, 256, 0, stream>>>(h1, a1s, a1d, als1, ald1);
    k_agg1<<<(N_NODES + 3) / 4, 256, 0, stream>>>(h1, csr, eid, srcA, als1, ald1, b1, o1);
    k_gemm2<<<(N_NODES + 31) / 32, 256, 0, stream>>>(o1, W2, h2);
    k_al2<<<(N_NODES + 7) / 8, 256, 0, stream>>>(h2, a2s, a2d, als2, ald2);
    k_agg2<<<(N_NODES + 3) / 4, 256, 0, stream>>>(h2, csr, eid, srcA, als2, ald2, b2, o2);
    k_poolfinal<<<NGRAPH, 256, 0, stream>>>(o2, goff, Wl, bl, out);
}

// Round 3
// 318.711 us; speedup vs baseline: 2.3644x; 1.4814x over previous
//
#include <hip/hip_runtime.h>
#include <math.h>

#define N_NODES 50000
#define N_EDGES 800000
#define EP      (N_EDGES + N_NODES)   // edges incl. self loops
#define IN_CH   128
#define HIDC    32
#define HEADS   4
#define OUTC    10
#define NGRAPH  64
#define NEG_SLOPE 0.2f

typedef unsigned int uint;

__device__ __forceinline__ float lrelu(float x) { return x > 0.f ? x : NEG_SLOPE * x; }
__device__ __forceinline__ float eluf(float x)  { return x > 0.f ? x : __expf(x) - 1.f; }

// pack two floats to bf16 pair (round-to-nearest-even), lo in bits 0..15
__device__ __forceinline__ uint bfpair(float lo, float hi) {
    uint a = __float_as_uint(lo), b = __float_as_uint(hi);
    a = (a + 0x7FFFu + ((a >> 16) & 1u)) >> 16;
    b = (b + 0x7FFFu + ((b >> 16) & 1u)) >> 16;
    return a | (b << 16);
}
__device__ __forceinline__ float bflo(uint d) { return __uint_as_float(d << 16); }
__device__ __forceinline__ float bfhi(uint d) { return __uint_as_float(d & 0xFFFF0000u); }

// ---------------- init ----------------
__global__ void k_init(int* __restrict__ indeg) {
    int i = blockIdx.x * 256 + threadIdx.x;
    if (i < N_NODES) indeg[i] = 1;              // self loop
}

// ---------------- CSR build ----------------
__global__ void k_count(const int* __restrict__ dst, int* __restrict__ indeg) {
    int e = blockIdx.x * 256 + threadIdx.x;
    if (e < N_EDGES) atomicAdd(&indeg[dst[e]], 1);
}

__global__ void k_scan1(const int* __restrict__ indeg, int* __restrict__ incl, int* __restrict__ bsum) {
    __shared__ int s[256];
    int t = threadIdx.x;
    int i = blockIdx.x * 256 + t;
    int v = (i < N_NODES) ? indeg[i] : 0;
    s[t] = v; __syncthreads();
    for (int off = 1; off < 256; off <<= 1) {
        int x = (t >= off) ? s[t - off] : 0;
        __syncthreads();
        s[t] += x;
        __syncthreads();
    }
    if (i < N_NODES) incl[i] = s[t];
    if (t == 255) bsum[blockIdx.x] = s[255];
}

__global__ void k_scan2(int* __restrict__ bsum, int nb) {
    __shared__ int s[256];
    int t = threadIdx.x;
    int v = (t < nb) ? bsum[t] : 0;
    s[t] = v; __syncthreads();
    for (int off = 1; off < 256; off <<= 1) {
        int x = (t >= off) ? s[t - off] : 0;
        __syncthreads();
        s[t] += x;
        __syncthreads();
    }
    if (t < nb) bsum[t] = s[t] - v;   // exclusive
}

__global__ void k_scan3(const int* __restrict__ indeg, int* __restrict__ csr,
                        const int* __restrict__ boff, int* __restrict__ pos) {
    int i = blockIdx.x * 256 + threadIdx.x;
    if (i >= N_NODES) return;
    int inc = csr[i] + boff[i >> 8];
    int ex = inc - indeg[i];
    csr[i] = ex;
    pos[i] = ex;
    if (i == N_NODES - 1) csr[N_NODES] = inc;
}

// store SOURCE NODE directly in the slot (no eid indirection)
__global__ void k_scatter(const int* __restrict__ src, const int* __restrict__ dst,
                          int* __restrict__ pos, int* __restrict__ esrc) {
    int t = blockIdx.x * 256 + threadIdx.x;
    if (t < N_EDGES) {
        int d = dst[t];
        int p = atomicAdd(&pos[d], 1);
        esrc[p] = src[t];
    } else if (t < EP) {
        int n = t - N_EDGES;
        int p = atomicAdd(&pos[n], 1);
        esrc[p] = n;                  // self loop
    }
}

// ---------------- graph boundaries (batch is sorted) ----------------
__global__ void k_bounds(const int* __restrict__ batch, int* __restrict__ goff) {
    int g = threadIdx.x;
    if (g > NGRAPH) return;
    int lo = 0, hi = N_NODES;
    while (lo < hi) {
        int mid = (lo + hi) >> 1;
        if (batch[mid] < g) lo = mid + 1; else hi = mid;
    }
    goff[g] = lo;
}

// ---------------- GEMM1: h1 = x @ W1 (128->128), fused als/ald + bf16 pack ----------------
__global__ __launch_bounds__(256) void k_gemm1(const float* __restrict__ x,
                                               const float* __restrict__ W,
                                               const float* __restrict__ a1s,
                                               const float* __restrict__ a1d,
                                               uint* __restrict__ h1b,
                                               float* __restrict__ als,
                                               float* __restrict__ ald) {
    __shared__ float Ws[128 * 128];   // 64 KB
    __shared__ float Xs[32 * 128];    // 16 KB (reused for reduction after main loop)
    int t = threadIdx.x;
    int row0 = blockIdx.x * 32;
    for (int idx = t * 4; idx < 128 * 128; idx += 1024)
        *(float4*)&Ws[idx] = *(const float4*)&W[idx];
    for (int idx = t * 4; idx < 32 * 128; idx += 1024) {
        int gr = row0 + (idx >> 7);
        float4 v = {0.f, 0.f, 0.f, 0.f};
        if (gr < N_NODES) v = *(const float4*)&x[gr * 128 + (idx & 127)];
        *(float4*)&Xs[idx] = v;
    }
    __syncthreads();
    int rp = t >> 4;              // 0..15
    int cg = t & 15;
    int jg = cg * 8;              // col base
    float4 a00 = {0,0,0,0}, a01 = {0,0,0,0}, a10 = {0,0,0,0}, a11 = {0,0,0,0};
#pragma unroll 4
    for (int k = 0; k < 128; k++) {
        float xv0 = Xs[rp * 128 + k];
        float xv1 = Xs[(rp + 16) * 128 + k];
        float4 wa = *(float4*)&Ws[k * 128 + jg];
        float4 wb = *(float4*)&Ws[k * 128 + jg + 4];
        a00.x += xv0 * wa.x; a00.y += xv0 * wa.y; a00.z += xv0 * wa.z; a00.w += xv0 * wa.w;
        a01.x += xv0 * wb.x; a01.y += xv0 * wb.y; a01.z += xv0 * wb.z; a01.w += xv0 * wb.w;
        a10.x += xv1 * wa.x; a10.y += xv1 * wa.y; a10.z += xv1 * wa.z; a10.w += xv1 * wa.w;
        a11.x += xv1 * wb.x; a11.y += xv1 * wb.y; a11.z += xv1 * wb.z; a11.w += xv1 * wb.w;
    }
    // ---- epilogue: attention-logit partials ----
    float4 vs0 = *(const float4*)&a1s[jg], vs1 = *(const float4*)&a1s[jg + 4];
    float4 vd0 = *(const float4*)&a1d[jg], vd1 = *(const float4*)&a1d[jg + 4];
    float ps0 = a00.x*vs0.x + a00.y*vs0.y + a00.z*vs0.z + a00.w*vs0.w
              + a01.x*vs1.x + a01.y*vs1.y + a01.z*vs1.z + a01.w*vs1.w;
    float ps1 = a10.x*vs0.x + a10.y*vs0.y + a10.z*vs0.z + a10.w*vs0.w
              + a11.x*vs1.x + a11.y*vs1.y + a11.z*vs1.z + a11.w*vs1.w;
    float pd0 = a00.x*vd0.x + a00.y*vd0.y + a00.z*vd0.z + a00.w*vd0.w
              + a01.x*vd1.x + a01.y*vd1.y + a01.z*vd1.z + a01.w*vd1.w;
    float pd1 = a10.x*vd0.x + a10.y*vd0.y + a10.z*vd0.z + a10.w*vd0.w
              + a11.x*vd1.x + a11.y*vd1.y + a11.z*vd1.z + a11.w*vd1.w;
    __syncthreads();                  // done reading Xs; reuse as reduction scratch
    float* rs = Xs;                   // [32][16]
    float* rd = Xs + 512;             // [32][16]
    rs[rp * 16 + cg] = ps0; rs[(rp + 16) * 16 + cg] = ps1;
    rd[rp * 16 + cg] = pd0; rd[(rp + 16) * 16 + cg] = pd1;
    __syncthreads();
    if (t < 128) {
        int row = t >> 2, head = t & 3;
        int gr = row0 + row;
        if (gr < N_NODES) {
            int b = row * 16 + head * 4;
            als[gr * 4 + head] = rs[b] + rs[b+1] + rs[b+2] + rs[b+3];
            ald[gr * 4 + head] = rd[b] + rd[b+1] + rd[b+2] + rd[b+3];
        }
    }
    // ---- bf16 pack: dword d holds channels (2d, 2d+1) ----
    int r0 = row0 + rp, r1 = row0 + rp + 16;
    if (r0 < N_NODES) {
        uint4 p = { bfpair(a00.x,a00.y), bfpair(a00.z,a00.w),
                    bfpair(a01.x,a01.y), bfpair(a01.z,a01.w) };
        *(uint4*)&h1b[r0 * 64 + cg * 4] = p;
    }
    if (r1 < N_NODES) {
        uint4 p = { bfpair(a10.x,a10.y), bfpair(a10.z,a10.w),
                    bfpair(a11.x,a11.y), bfpair(a11.z,a11.w) };
        *(uint4*)&h1b[r1 * 64 + cg * 4] = p;
    }
}

// ---------------- aggregation conv1: wave per node (grid must be exactly N/4 blocks) ----------------
__global__ __launch_bounds__(256) void k_agg1(const uint* __restrict__ h1b,
                                              const int* __restrict__ csr, const int* __restrict__ esrc,
                                              const float* __restrict__ als, const float* __restrict__ ald,
                                              const float* __restrict__ b1,
                                              float* __restrict__ alf,
                                              float* __restrict__ o1) {
    int l = threadIdx.x & 63;
    int n = blockIdx.x * 4 + (threadIdx.x >> 6);
    int s = csr[n], e = csr[n + 1];
    float4 ad = *(const float4*)&ald[n * 4];
    // pass 1: max per head
    float m0 = -INFINITY, m1 = -INFINITY, m2 = -INFINITY, m3 = -INFINITY;
    for (int i = s + l; i < e; i += 64) {
        int sc = esrc[i];
        float4 av = *(const float4*)&als[sc * 4];
        m0 = fmaxf(m0, lrelu(av.x + ad.x));
        m1 = fmaxf(m1, lrelu(av.y + ad.y));
        m2 = fmaxf(m2, lrelu(av.z + ad.z));
        m3 = fmaxf(m3, lrelu(av.w + ad.w));
    }
    for (int off = 1; off < 64; off <<= 1) {
        m0 = fmaxf(m0, __shfl_xor(m0, off));
        m1 = fmaxf(m1, __shfl_xor(m1, off));
        m2 = fmaxf(m2, __shfl_xor(m2, off));
        m3 = fmaxf(m3, __shfl_xor(m3, off));
    }
    // pass 2: exp, stash unnormalized, sum
    float s0 = 0, s1 = 0, s2 = 0, s3 = 0;
    for (int i = s + l; i < e; i += 64) {
        int sc = esrc[i];
        float4 av = *(const float4*)&als[sc * 4];
        float e0 = __expf(lrelu(av.x + ad.x) - m0);
        float e1 = __expf(lrelu(av.y + ad.y) - m1);
        float e2 = __expf(lrelu(av.z + ad.z) - m2);
        float e3 = __expf(lrelu(av.w + ad.w) - m3);
        float4 ev = {e0, e1, e2, e3};
        *(float4*)&alf[i * 4] = ev;
        s0 += e0; s1 += e1; s2 += e2; s3 += e3;
    }
    for (int off = 1; off < 64; off <<= 1) {
        s0 += __shfl_xor(s0, off); s1 += __shfl_xor(s1, off);
        s2 += __shfl_xor(s2, off); s3 += __shfl_xor(s3, off);
    }
    int hh = l >> 4;                 // head of this lane's channel pair
    float sd = (hh == 0) ? s0 : (hh == 1) ? s1 : (hh == 2) ? s2 : s3;
    float inv = 1.f / sd;
    __syncthreads();                 // make alf stores visible / drain
    // pass 3: pure gather + FMA, channels (2l, 2l+1)
    float acc0 = 0.f, acc1 = 0.f;
    int i = s;
    for (; i + 1 < e; i += 2) {
        int sa = esrc[i], sb = esrc[i + 1];
        float a0 = alf[i * 4 + hh];
        float a1 = alf[i * 4 + 4 + hh];
        uint d0 = h1b[sa * 64 + l];
        uint d1 = h1b[sb * 64 + l];
        a0 *= inv; a1 *= inv;
        acc0 += a0 * bflo(d0); acc1 += a0 * bfhi(d0);
        acc0 += a1 * bflo(d1); acc1 += a1 * bfhi(d1);
    }
    if (i < e) {
        int sa = esrc[i];
        float a0 = alf[i * 4 + hh] * inv;
        uint d0 = h1b[sa * 64 + l];
        acc0 += a0 * bflo(d0); acc1 += a0 * bfhi(d0);
    }
    float2 bb = *(const float2*)&b1[2 * l];
    float2 o = { eluf(acc0 + bb.x), eluf(acc1 + bb.y) };
    *(float2*)&o1[n * 128 + 2 * l] = o;
}

// ---------------- GEMM2: h2 = o1 @ W2 (128->32), fused als/ald + bf16 pack ----------------
__global__ __launch_bounds__(256) void k_gemm2(const float* __restrict__ x,
                                               const float* __restrict__ W,
                                               const float* __restrict__ a2s,
                                               const float* __restrict__ a2d,
                                               uint* __restrict__ h2b,
                                               float* __restrict__ als,
                                               float* __restrict__ ald) {
    __shared__ float Ws[128 * 32];    // 16 KB
    __shared__ float Xs[32 * 128];    // 16 KB (reused after main loop)
    int t = threadIdx.x;
    int row0 = blockIdx.x * 32;
    for (int idx = t * 4; idx < 128 * 32; idx += 1024)
        *(float4*)&Ws[idx] = *(const float4*)&W[idx];
    for (int idx = t * 4; idx < 32 * 128; idx += 1024) {
        int gr = row0 + (idx >> 7);
        float4 v = {0.f, 0.f, 0.f, 0.f};
        if (gr < N_NODES) v = *(const float4*)&x[gr * 128 + (idx & 127)];
        *(float4*)&Xs[idx] = v;
    }
    __syncthreads();
    int r = t >> 3;
    int cg = t & 7;
    int jg = cg * 4;
    float a0 = 0, a1 = 0, a2 = 0, a3 = 0;
#pragma unroll 4
    for (int k = 0; k < 128; k++) {
        float xv = Xs[r * 128 + k];
        float4 w = *(float4*)&Ws[k * 32 + jg];
        a0 += xv * w.x; a1 += xv * w.y; a2 += xv * w.z; a3 += xv * w.w;
    }
    float4 vs = *(const float4*)&a2s[jg];
    float4 vd = *(const float4*)&a2d[jg];
    float ps = a0*vs.x + a1*vs.y + a2*vs.z + a3*vs.w;
    float pd = a0*vd.x + a1*vd.y + a2*vd.z + a3*vd.w;
    __syncthreads();
    float* rs = Xs;                   // [32][8]
    float* rd = Xs + 256;             // [32][8]
    rs[r * 8 + cg] = ps;
    rd[r * 8 + cg] = pd;
    __syncthreads();
    int gr = row0 + r;
    if (gr < N_NODES) {
        uint2 p = { bfpair(a0, a1), bfpair(a2, a3) };
        *(uint2*)&h2b[gr * 16 + cg * 2] = p;
    }
    if (t < 32) {
        int g2 = row0 + t;
        if (g2 < N_NODES) {
            float ss = 0, dd = 0;
#pragma unroll
            for (int k2 = 0; k2 < 8; k2++) { ss += rs[t * 8 + k2]; dd += rd[t * 8 + k2]; }
            als[g2] = ss; ald[g2] = dd;
        }
    }
}

// ---------------- aggregation conv2: wave per node (grid exactly N/4) ----------------
__global__ __launch_bounds__(256) void k_agg2(const uint* __restrict__ h2b,
                                              const int* __restrict__ csr, const int* __restrict__ esrc,
                                              const float* __restrict__ als, const float* __restrict__ ald,
                                              const float* __restrict__ b2,
                                              float* __restrict__ alf2,
                                              float* __restrict__ o2) {
    int l = threadIdx.x & 63;
    int n = blockIdx.x * 4 + (threadIdx.x >> 6);
    int s = csr[n], e = csr[n + 1];
    float ad = ald[n];
    float m = -INFINITY;
    for (int i = s + l; i < e; i += 64)
        m = fmaxf(m, lrelu(als[esrc[i]] + ad));
    for (int off = 1; off < 64; off <<= 1) m = fmaxf(m, __shfl_xor(m, off));
    float sum = 0.f;
    for (int i = s + l; i < e; i += 64) {
        float ex = __expf(lrelu(als[esrc[i]] + ad) - m);
        alf2[i] = ex;
        sum += ex;
    }
    for (int off = 1; off < 64; off <<= 1) sum += __shfl_xor(sum, off);
    float inv = 1.f / sum;
    __syncthreads();
    // 4 edges in parallel; lane handles channel pair (2cp, 2cp+1)
    int el = l >> 4, cp = l & 15;
    float acc0 = 0.f, acc1 = 0.f;
    for (int i = s + el; i < e; i += 4) {
        int sc = esrc[i];
        float a = alf2[i] * inv;
        uint d = h2b[sc * 16 + cp];
        acc0 += a * bflo(d); acc1 += a * bfhi(d);
    }
    acc0 += __shfl_xor(acc0, 16); acc0 += __shfl_xor(acc0, 32);
    acc1 += __shfl_xor(acc1, 16); acc1 += __shfl_xor(acc1, 32);
    if (l < 16) {
        float2 bb = *(const float2*)&b2[2 * cp];
        float2 o = { eluf(acc0 + bb.x), eluf(acc1 + bb.y) };
        *(float2*)&o2[n * 32 + 2 * cp] = o;
    }
}

// ---------------- fused pool + final linear ----------------
__global__ __launch_bounds__(256) void k_poolfinal(const float* __restrict__ out2,
                                                   const int* __restrict__ goff,
                                                   const float* __restrict__ Wl,
                                                   const float* __restrict__ bl,
                                                   float* __restrict__ out) {
    __shared__ float red[4][32];
    __shared__ float pooled[32];
    int g = blockIdx.x;
    int s = goff[g], e = goff[g + 1];
    int t = threadIdx.x;
    int c = t & 31, r = t >> 5;           // 8 rows per sweep
    float acc = 0.f;
    for (int i = s + r; i < e; i += 8)
        acc += out2[i * 32 + c];
    acc += __shfl_xor(acc, 32);           // combine 2 rows within wave
    if ((t & 63) < 32) red[t >> 6][c] = acc;
    __syncthreads();
    if (t < 32) {
        float v = red[0][t] + red[1][t] + red[2][t] + red[3][t];
        float cnt = fmaxf((float)(e - s), 1.f);
        pooled[t] = v / cnt;
    }
    __syncthreads();
    if (t < OUTC) {
        float a = 0.f;
        for (int cc = 0; cc < HIDC; cc++)
            a += pooled[cc] * Wl[cc * OUTC + t];
        out[g * OUTC + t] = a + bl[t];
    }
}

extern "C" void kernel_launch(void* const* d_in, const int* in_sizes, int n_in,
                              void* d_out, int out_size, void* d_ws, size_t ws_size,
                              hipStream_t stream) {
    (void)in_sizes; (void)n_in; (void)out_size; (void)ws_size;
    const float* x    = (const float*)d_in[0];
    const int*   ei   = (const int*)d_in[1];
    const int*   srcA = ei;
    const int*   dstA = ei + N_EDGES;
    const int*   batch = (const int*)d_in[2];
    const float* W1  = (const float*)d_in[3];
    const float* a1s = (const float*)d_in[4];
    const float* a1d = (const float*)d_in[5];
    const float* b1  = (const float*)d_in[6];
    const float* W2  = (const float*)d_in[7];
    const float* a2s = (const float*)d_in[8];
    const float* a2d = (const float*)d_in[9];
    const float* b2  = (const float*)d_in[10];
    const float* Wl  = (const float*)d_in[11];
    const float* bl  = (const float*)d_in[12];
    float* out = (float*)d_out;

    char* w = (char*)d_ws;
    auto alloc = [&](size_t bytes) -> void* {
        void* p = (void*)w;
        w += (bytes + 255) & ~(size_t)255;
        return p;
    };
    uint*  h1b  = (uint*)alloc((size_t)N_NODES * 64 * 4);    // 12.8 MB
    float* o1   = (float*)alloc((size_t)N_NODES * 128 * 4);  // 25.6 MB
    float* als1 = (float*)alloc((size_t)N_NODES * 4 * 4);
    float* ald1 = (float*)alloc((size_t)N_NODES * 4 * 4);
    uint*  h2b  = (uint*)alloc((size_t)N_NODES * 16 * 4);    // 3.2 MB
    float* o2   = (float*)alloc((size_t)N_NODES * 32 * 4);   // 6.4 MB
    float* als2 = (float*)alloc((size_t)N_NODES * 4);
    float* ald2 = (float*)alloc((size_t)N_NODES * 4);
    float* alf  = (float*)alloc((size_t)EP * 4 * 4);         // 13.6 MB
    float* alf2 = (float*)alloc((size_t)EP * 4);             // 3.4 MB
    int*   indeg = (int*)alloc((size_t)N_NODES * 4);
    int*   csr   = (int*)alloc((size_t)(N_NODES + 1) * 4);
    int*   pos   = (int*)alloc((size_t)N_NODES * 4);
    int*   esrc  = (int*)alloc((size_t)EP * 4);
    int*   bsum  = (int*)alloc(256 * 4);
    int*   goff  = (int*)alloc((size_t)(NGRAPH + 1) * 4);

    int nb = (N_NODES + 255) / 256;   // 196

    k_init<<<nb, 256, 0, stream>>>(indeg);
    k_count<<<(N_EDGES + 255) / 256, 256, 0, stream>>>(dstA, indeg);
    k_scan1<<<nb, 256, 0, stream>>>(indeg, csr, bsum);
    k_scan2<<<1, 256, 0, stream>>>(bsum, nb);
    k_scan3<<<nb, 256, 0, stream>>>(indeg, csr, bsum, pos);
    k_scatter<<<(EP + 255) / 256, 256, 0, stream>>>(srcA, dstA, pos, esrc);
    k_bounds<<<1, 128, 0, stream>>>(batch, goff);
    k_gemm1<<<(N_NODES + 31) / 32, 256, 0, stream>>>(x, W1, a1s, a1d, h1b, als1, ald1);
    k_agg1<<<N_NODES / 4, 256, 0, stream>>>(h1b, csr, esrc, als1, ald1, b1, alf, o1);
    k_gemm2<<<(N_NODES + 31) / 32, 256, 0, stream>>>(o1, W2, a2s, a2d, h2b, als2, ald2);
    k_agg2<<<N_NODES / 4, 256, 0, stream>>>(h2b, csr, esrc, als2, ald2, b2, alf2, o2);
    k_poolfinal<<<NGRAPH, 256, 0, stream>>>(o2, goff, Wl, bl, out);
}

// Round 4
// 300.566 us; speedup vs baseline: 2.5071x; 1.0604x over previous
//
#include <hip/hip_runtime.h>
#include <math.h>

#define N_NODES 50000
#define N_EDGES 800000
#define EP      (N_EDGES + N_NODES)   // edges incl. self loops
#define IN_CH   128
#define HIDC    32
#define HEADS   4
#define OUTC    10
#define NGRAPH  64
#define NEG_SLOPE 0.2f

typedef unsigned int uint;

__device__ __forceinline__ float lrelu(float x) { return x > 0.f ? x : NEG_SLOPE * x; }
__device__ __forceinline__ float eluf(float x)  { return x > 0.f ? x : __expf(x) - 1.f; }

// pack two floats to bf16 pair (round-to-nearest-even), lo in bits 0..15
__device__ __forceinline__ uint bfpair(float lo, float hi) {
    uint a = __float_as_uint(lo), b = __float_as_uint(hi);
    a = (a + 0x7FFFu + ((a >> 16) & 1u)) >> 16;
    b = (b + 0x7FFFu + ((b >> 16) & 1u)) >> 16;
    return a | (b << 16);
}
__device__ __forceinline__ float bflo(uint d) { return __uint_as_float(d << 16); }
__device__ __forceinline__ float bfhi(uint d) { return __uint_as_float(d & 0xFFFF0000u); }

// ---------------- CSR build ----------------
__global__ void k_count(const int* __restrict__ dst, int* __restrict__ indeg) {
    int e = blockIdx.x * 256 + threadIdx.x;
    if (e < N_EDGES) atomicAdd(&indeg[dst[e]], 1);
}

// inclusive scan of (indeg[i] + 1)  (+1 = self loop)
__global__ void k_scan1(const int* __restrict__ indeg, int* __restrict__ incl, int* __restrict__ bsum) {
    __shared__ int s[256];
    int t = threadIdx.x;
    int i = blockIdx.x * 256 + t;
    int v = (i < N_NODES) ? indeg[i] + 1 : 0;
    s[t] = v; __syncthreads();
    for (int off = 1; off < 256; off <<= 1) {
        int x = (t >= off) ? s[t - off] : 0;
        __syncthreads();
        s[t] += x;
        __syncthreads();
    }
    if (i < N_NODES) incl[i] = s[t];
    if (t == 255) bsum[blockIdx.x] = s[255];
}

__global__ void k_scan2(int* __restrict__ bsum, int nb) {
    __shared__ int s[256];
    int t = threadIdx.x;
    int v = (t < nb) ? bsum[t] : 0;
    s[t] = v; __syncthreads();
    for (int off = 1; off < 256; off <<= 1) {
        int x = (t >= off) ? s[t - off] : 0;
        __syncthreads();
        s[t] += x;
        __syncthreads();
    }
    if (t < nb) bsum[t] = s[t] - v;   // exclusive
}

__global__ void k_scan3(const int* __restrict__ indeg, int* __restrict__ csr,
                        const int* __restrict__ boff, int* __restrict__ pos) {
    int i = blockIdx.x * 256 + threadIdx.x;
    if (i >= N_NODES) return;
    int inc = csr[i] + boff[i >> 8];
    int ex = inc - indeg[i] - 1;
    csr[i] = ex;
    pos[i] = ex;
    if (i == N_NODES - 1) csr[N_NODES] = inc;
}

// store SOURCE NODE directly in the slot (no eid indirection)
__global__ void k_scatter(const int* __restrict__ src, const int* __restrict__ dst,
                          int* __restrict__ pos, int* __restrict__ esrc) {
    int t = blockIdx.x * 256 + threadIdx.x;
    if (t < N_EDGES) {
        int d = dst[t];
        int p = atomicAdd(&pos[d], 1);
        esrc[p] = src[t];
    } else if (t < EP) {
        int n = t - N_EDGES;
        int p = atomicAdd(&pos[n], 1);
        esrc[p] = n;                  // self loop
    }
}

// ---------------- GEMM1: h1 = x @ W1 (128->128), fused als/ald + bf16 pack ----------------
// Xs stored TRANSPOSED (Xs[k][row]) -> broadcast reads hit distinct banks.
__global__ __launch_bounds__(256) void k_gemm1(const float* __restrict__ x,
                                               const float* __restrict__ W,
                                               const float* __restrict__ a1s,
                                               const float* __restrict__ a1d,
                                               uint* __restrict__ h1b,
                                               float* __restrict__ als,
                                               float* __restrict__ ald) {
    __shared__ float Ws[128 * 128];   // 64 KB
    __shared__ float Xs[128 * 32];    // 16 KB, transposed; reused as scratch after loop
    int t = threadIdx.x;
    int row0 = blockIdx.x * 32;
    for (int idx = t * 4; idx < 128 * 128; idx += 1024)
        *(float4*)&Ws[idx] = *(const float4*)&W[idx];
    for (int idx = t * 4; idx < 32 * 128; idx += 1024) {
        int row = idx >> 7, col = idx & 127;
        int gr = row0 + row;
        float4 v = {0.f, 0.f, 0.f, 0.f};
        if (gr < N_NODES) v = *(const float4*)&x[gr * 128 + col];
        Xs[(col + 0) * 32 + row] = v.x;
        Xs[(col + 1) * 32 + row] = v.y;
        Xs[(col + 2) * 32 + row] = v.z;
        Xs[(col + 3) * 32 + row] = v.w;
    }
    __syncthreads();
    int rp = t >> 4;              // 0..15
    int cg = t & 15;
    int jg = cg * 8;              // col base
    float4 a00 = {0,0,0,0}, a01 = {0,0,0,0}, a10 = {0,0,0,0}, a11 = {0,0,0,0};
#pragma unroll 4
    for (int k = 0; k < 128; k++) {
        float xv0 = Xs[k * 32 + rp];
        float xv1 = Xs[k * 32 + rp + 16];
        float4 wa = *(float4*)&Ws[k * 128 + jg];
        float4 wb = *(float4*)&Ws[k * 128 + jg + 4];
        a00.x += xv0 * wa.x; a00.y += xv0 * wa.y; a00.z += xv0 * wa.z; a00.w += xv0 * wa.w;
        a01.x += xv0 * wb.x; a01.y += xv0 * wb.y; a01.z += xv0 * wb.z; a01.w += xv0 * wb.w;
        a10.x += xv1 * wa.x; a10.y += xv1 * wa.y; a10.z += xv1 * wa.z; a10.w += xv1 * wa.w;
        a11.x += xv1 * wb.x; a11.y += xv1 * wb.y; a11.z += xv1 * wb.z; a11.w += xv1 * wb.w;
    }
    // ---- epilogue: attention-logit partials ----
    float4 vs0 = *(const float4*)&a1s[jg], vs1 = *(const float4*)&a1s[jg + 4];
    float4 vd0 = *(const float4*)&a1d[jg], vd1 = *(const float4*)&a1d[jg + 4];
    float ps0 = a00.x*vs0.x + a00.y*vs0.y + a00.z*vs0.z + a00.w*vs0.w
              + a01.x*vs1.x + a01.y*vs1.y + a01.z*vs1.z + a01.w*vs1.w;
    float ps1 = a10.x*vs0.x + a10.y*vs0.y + a10.z*vs0.z + a10.w*vs0.w
              + a11.x*vs1.x + a11.y*vs1.y + a11.z*vs1.z + a11.w*vs1.w;
    float pd0 = a00.x*vd0.x + a00.y*vd0.y + a00.z*vd0.z + a00.w*vd0.w
              + a01.x*vd1.x + a01.y*vd1.y + a01.z*vd1.z + a01.w*vd1.w;
    float pd1 = a10.x*vd0.x + a10.y*vd0.y + a10.z*vd0.z + a10.w*vd0.w
              + a11.x*vd1.x + a11.y*vd1.y + a11.z*vd1.z + a11.w*vd1.w;
    __syncthreads();                  // done reading Xs; reuse as reduction scratch
    float* rs = Xs;                   // [32][16]
    float* rd = Xs + 512;             // [32][16]
    rs[rp * 16 + cg] = ps0; rs[(rp + 16) * 16 + cg] = ps1;
    rd[rp * 16 + cg] = pd0; rd[(rp + 16) * 16 + cg] = pd1;
    __syncthreads();
    if (t < 128) {
        int row = t >> 2, head = t & 3;
        int gr = row0 + row;
        if (gr < N_NODES) {
            int b = row * 16 + head * 4;
            als[gr * 4 + head] = rs[b] + rs[b+1] + rs[b+2] + rs[b+3];
            ald[gr * 4 + head] = rd[b] + rd[b+1] + rd[b+2] + rd[b+3];
        }
    }
    // ---- bf16 pack: dword d holds channels (2d, 2d+1) ----
    int r0 = row0 + rp, r1 = row0 + rp + 16;
    if (r0 < N_NODES) {
        uint4 p = { bfpair(a00.x,a00.y), bfpair(a00.z,a00.w),
                    bfpair(a01.x,a01.y), bfpair(a01.z,a01.w) };
        *(uint4*)&h1b[r0 * 64 + cg * 4] = p;
    }
    if (r1 < N_NODES) {
        uint4 p = { bfpair(a10.x,a10.y), bfpair(a10.z,a10.w),
                    bfpair(a11.x,a11.y), bfpair(a11.z,a11.w) };
        *(uint4*)&h1b[r1 * 64 + cg * 4] = p;
    }
}

// ---------------- aggregation conv1: SINGLE PASS, wave per node ----------------
// No max-stabilization (softmax shift-invariant; |logit| << 88).
// Half-wave per edge: lanes 0-31 edge i, lanes 32-63 edge i+1. 4 channels/lane.
__global__ __launch_bounds__(256) void k_agg1(const uint* __restrict__ h1b,
                                              const int* __restrict__ csr, const int* __restrict__ esrc,
                                              const float* __restrict__ als, const float* __restrict__ ald,
                                              const float* __restrict__ b1,
                                              float* __restrict__ o1) {
    int l = threadIdx.x & 63;
    int n = blockIdx.x * 4 + (threadIdx.x >> 6);
    int s = csr[n], e = csr[n + 1];
    int cp = l & 31, half = l >> 5;
    int hh = cp >> 3;                 // head of channels 4cp..4cp+3
    float adh = ald[n * 4 + hh];
    float acc0 = 0.f, acc1 = 0.f, acc2 = 0.f, acc3 = 0.f, ssum = 0.f;
#pragma unroll 2
    for (int i = s + half; i < e; i += 2) {
        int sa = esrc[i];
        float ex = __expf(lrelu(als[sa * 4 + hh] + adh));
        ssum += ex;
        uint2 d = *(const uint2*)&h1b[sa * 64 + cp * 2];
        acc0 += ex * bflo(d.x); acc1 += ex * bfhi(d.x);
        acc2 += ex * bflo(d.y); acc3 += ex * bfhi(d.y);
    }
    acc0 += __shfl_xor(acc0, 32); acc1 += __shfl_xor(acc1, 32);
    acc2 += __shfl_xor(acc2, 32); acc3 += __shfl_xor(acc3, 32);
    ssum += __shfl_xor(ssum, 32);
    if (half == 0) {
        float inv = 1.f / ssum;
        float4 bb = *(const float4*)&b1[cp * 4];
        float4 o = { eluf(acc0 * inv + bb.x), eluf(acc1 * inv + bb.y),
                     eluf(acc2 * inv + bb.z), eluf(acc3 * inv + bb.w) };
        *(float4*)&o1[n * 128 + cp * 4] = o;
    }
}

// ---------------- GEMM2: h2 = o1 @ W2 (128->32), fused als/ald + bf16 pack ----------------
__global__ __launch_bounds__(256) void k_gemm2(const float* __restrict__ x,
                                               const float* __restrict__ W,
                                               const float* __restrict__ a2s,
                                               const float* __restrict__ a2d,
                                               uint* __restrict__ h2b,
                                               float* __restrict__ als,
                                               float* __restrict__ ald) {
    __shared__ float Ws[128 * 32];    // 16 KB
    __shared__ float Xs[128 * 32];    // 16 KB, transposed; reused after loop
    int t = threadIdx.x;
    int row0 = blockIdx.x * 32;
    for (int idx = t * 4; idx < 128 * 32; idx += 1024)
        *(float4*)&Ws[idx] = *(const float4*)&W[idx];
    for (int idx = t * 4; idx < 32 * 128; idx += 1024) {
        int row = idx >> 7, col = idx & 127;
        int gr = row0 + row;
        float4 v = {0.f, 0.f, 0.f, 0.f};
        if (gr < N_NODES) v = *(const float4*)&x[gr * 128 + col];
        Xs[(col + 0) * 32 + row] = v.x;
        Xs[(col + 1) * 32 + row] = v.y;
        Xs[(col + 2) * 32 + row] = v.z;
        Xs[(col + 3) * 32 + row] = v.w;
    }
    __syncthreads();
    int r = t >> 3;
    int cg = t & 7;
    int jg = cg * 4;
    float a0 = 0, a1 = 0, a2 = 0, a3 = 0;
#pragma unroll 4
    for (int k = 0; k < 128; k++) {
        float xv = Xs[k * 32 + r];
        float4 w = *(float4*)&Ws[k * 32 + jg];
        a0 += xv * w.x; a1 += xv * w.y; a2 += xv * w.z; a3 += xv * w.w;
    }
    float4 vs = *(const float4*)&a2s[jg];
    float4 vd = *(const float4*)&a2d[jg];
    float ps = a0*vs.x + a1*vs.y + a2*vs.z + a3*vs.w;
    float pd = a0*vd.x + a1*vd.y + a2*vd.z + a3*vd.w;
    __syncthreads();
    float* rs = Xs;                   // [32][8]
    float* rd = Xs + 256;             // [32][8]
    rs[r * 8 + cg] = ps;
    rd[r * 8 + cg] = pd;
    __syncthreads();
    int gr = row0 + r;
    if (gr < N_NODES) {
        uint2 p = { bfpair(a0, a1), bfpair(a2, a3) };
        *(uint2*)&h2b[gr * 16 + cg * 2] = p;
    }
    if (t < 32) {
        int g2 = row0 + t;
        if (g2 < N_NODES) {
            float ss = 0, dd = 0;
#pragma unroll
            for (int k2 = 0; k2 < 8; k2++) { ss += rs[t * 8 + k2]; dd += rd[t * 8 + k2]; }
            als[g2] = ss; ald[g2] = dd;
        }
    }
}

// ---------------- aggregation conv2: SINGLE PASS, quarter-wave per edge ----------------
__global__ __launch_bounds__(256) void k_agg2(const uint* __restrict__ h2b,
                                              const int* __restrict__ csr, const int* __restrict__ esrc,
                                              const float* __restrict__ als, const float* __restrict__ ald,
                                              const float* __restrict__ b2,
                                              float* __restrict__ o2) {
    int l = threadIdx.x & 63;
    int n = blockIdx.x * 4 + (threadIdx.x >> 6);
    int s = csr[n], e = csr[n + 1];
    int cp = l & 15, sub = l >> 4;    // 4 edges in flight
    float ad = ald[n];
    float acc0 = 0.f, acc1 = 0.f, ssum = 0.f;
#pragma unroll 2
    for (int i = s + sub; i < e; i += 4) {
        int sa = esrc[i];
        float ex = __expf(lrelu(als[sa] + ad));
        ssum += ex;
        uint d = h2b[sa * 16 + cp];
        acc0 += ex * bflo(d); acc1 += ex * bfhi(d);
    }
    acc0 += __shfl_xor(acc0, 16); acc1 += __shfl_xor(acc1, 16); ssum += __shfl_xor(ssum, 16);
    acc0 += __shfl_xor(acc0, 32); acc1 += __shfl_xor(acc1, 32); ssum += __shfl_xor(ssum, 32);
    if (sub == 0) {
        float inv = 1.f / ssum;
        float2 bb = *(const float2*)&b2[cp * 2];
        float2 o = { eluf(acc0 * inv + bb.x), eluf(acc1 * inv + bb.y) };
        *(float2*)&o2[n * 32 + cp * 2] = o;
    }
}

// ---------------- fused pool + final linear (inline boundary search) ----------------
__global__ __launch_bounds__(256) void k_poolfinal(const float* __restrict__ out2,
                                                   const int* __restrict__ batch,
                                                   const float* __restrict__ Wl,
                                                   const float* __restrict__ bl,
                                                   float* __restrict__ out) {
    __shared__ float red[4][32];
    __shared__ float pooled[32];
    int g = blockIdx.x;
    // lower_bound(batch, g) and lower_bound(batch, g+1), all threads redundantly
    int s = 0, hi = N_NODES;
    while (s < hi) { int mid = (s + hi) >> 1; if (batch[mid] < g) s = mid + 1; else hi = mid; }
    int e = s; hi = N_NODES;
    while (e < hi) { int mid = (e + hi) >> 1; if (batch[mid] < g + 1) e = mid + 1; else hi = mid; }
    int t = threadIdx.x;
    int c = t & 31, r = t >> 5;           // 8 rows per sweep
    float acc = 0.f;
    for (int i = s + r; i < e; i += 8)
        acc += out2[i * 32 + c];
    acc += __shfl_xor(acc, 32);           // combine 2 rows within wave
    if ((t & 63) < 32) red[t >> 6][c] = acc;
    __syncthreads();
    if (t < 32) {
        float v = red[0][t] + red[1][t] + red[2][t] + red[3][t];
        float cnt = fmaxf((float)(e - s), 1.f);
        pooled[t] = v / cnt;
    }
    __syncthreads();
    if (t < OUTC) {
        float a = 0.f;
        for (int cc = 0; cc < HIDC; cc++)
            a += pooled[cc] * Wl[cc * OUTC + t];
        out[g * OUTC + t] = a + bl[t];
    }
}

extern "C" void kernel_launch(void* const* d_in, const int* in_sizes, int n_in,
                              void* d_out, int out_size, void* d_ws, size_t ws_size,
                              hipStream_t stream) {
    (void)in_sizes; (void)n_in; (void)out_size; (void)ws_size;
    const float* x    = (const float*)d_in[0];
    const int*   ei   = (const int*)d_in[1];
    const int*   srcA = ei;
    const int*   dstA = ei + N_EDGES;
    const int*   batch = (const int*)d_in[2];
    const float* W1  = (const float*)d_in[3];
    const float* a1s = (const float*)d_in[4];
    const float* a1d = (const float*)d_in[5];
    const float* b1  = (const float*)d_in[6];
    const float* W2  = (const float*)d_in[7];
    const float* a2s = (const float*)d_in[8];
    const float* a2d = (const float*)d_in[9];
    const float* b2  = (const float*)d_in[10];
    const float* Wl  = (const float*)d_in[11];
    const float* bl  = (const float*)d_in[12];
    float* out = (float*)d_out;

    char* w = (char*)d_ws;
    auto alloc = [&](size_t bytes) -> void* {
        void* p = (void*)w;
        w += (bytes + 255) & ~(size_t)255;
        return p;
    };
    uint*  h1b  = (uint*)alloc((size_t)N_NODES * 64 * 4);    // 12.8 MB
    float* o1   = (float*)alloc((size_t)N_NODES * 128 * 4);  // 25.6 MB
    float* als1 = (float*)alloc((size_t)N_NODES * 4 * 4);
    float* ald1 = (float*)alloc((size_t)N_NODES * 4 * 4);
    uint*  h2b  = (uint*)alloc((size_t)N_NODES * 16 * 4);    // 3.2 MB
    float* o2   = (float*)alloc((size_t)N_NODES * 32 * 4);   // 6.4 MB
    float* als2 = (float*)alloc((size_t)N_NODES * 4);
    float* ald2 = (float*)alloc((size_t)N_NODES * 4);
    int*   indeg = (int*)alloc((size_t)N_NODES * 4);
    int*   csr   = (int*)alloc((size_t)(N_NODES + 1) * 4);
    int*   pos   = (int*)alloc((size_t)N_NODES * 4);
    int*   esrc  = (int*)alloc((size_t)EP * 4);
    int*   bsum  = (int*)alloc(256 * 4);

    int nb = (N_NODES + 255) / 256;   // 196

    hipMemsetAsync(indeg, 0, (size_t)N_NODES * 4, stream);
    k_count<<<(N_EDGES + 255) / 256, 256, 0, stream>>>(dstA, indeg);
    k_scan1<<<nb, 256, 0, stream>>>(indeg, csr, bsum);
    k_scan2<<<1, 256, 0, stream>>>(bsum, nb);
    k_scan3<<<nb, 256, 0, stream>>>(indeg, csr, bsum, pos);
    k_scatter<<<(EP + 255) / 256, 256, 0, stream>>>(srcA, dstA, pos, esrc);
    k_gemm1<<<(N_NODES + 31) / 32, 256, 0, stream>>>(x, W1, a1s, a1d, h1b, als1, ald1);
    k_agg1<<<N_NODES / 4, 256, 0, stream>>>(h1b, csr, esrc, als1, ald1, b1, o1);
    k_gemm2<<<(N_NODES + 31) / 32, 256, 0, stream>>>(o1, W2, a2s, a2d, h2b, als2, ald2);
    k_agg2<<<N_NODES / 4, 256, 0, stream>>>(h2b, csr, esrc, als2, ald2, b2, o2);
    k_poolfinal<<<NGRAPH, 256, 0, stream>>>(o2, batch, Wl, bl, out);
}

// Round 5
// 250.380 us; speedup vs baseline: 3.0097x; 1.2004x over previous
//
#include <hip/hip_runtime.h>
#include <math.h>

#define N_NODES 50000
#define N_EDGES 800000
#define EP      (N_EDGES + N_NODES)   // edges incl. self loops
#define IN_CH   128
#define HIDC    32
#define HEADS   4
#define OUTC    10
#define NGRAPH  64
#define NEG_SLOPE 0.2f
#define NPAD    50176                  // 128-row padded node count

typedef unsigned int uint;
typedef __attribute__((ext_vector_type(8))) short bf16x8;
typedef __attribute__((ext_vector_type(4))) float f32x4;

__device__ __forceinline__ float lrelu(float x) { return x > 0.f ? x : NEG_SLOPE * x; }
__device__ __forceinline__ float eluf(float x)  { return x > 0.f ? x : __expf(x) - 1.f; }

__device__ __forceinline__ uint bfr(float f) {                 // f32 -> bf16 bits (RNE)
    uint a = __float_as_uint(f);
    return (a + 0x7FFFu + ((a >> 16) & 1u)) >> 16;
}
__device__ __forceinline__ uint bfpair(float lo, float hi) { return bfr(lo) | (bfr(hi) << 16); }
__device__ __forceinline__ float bflo(uint d) { return __uint_as_float(d << 16); }
__device__ __forceinline__ float bfhi(uint d) { return __uint_as_float(d & 0xFFFF0000u); }

// ---------------- CSR build ----------------
__global__ void k_count(const int* __restrict__ dst, int* __restrict__ indeg) {
    int e = blockIdx.x * 256 + threadIdx.x;
    if (e < N_EDGES) atomicAdd(&indeg[dst[e]], 1);
}

__global__ void k_scan1(const int* __restrict__ indeg, int* __restrict__ incl, int* __restrict__ bsum) {
    __shared__ int s[256];
    int t = threadIdx.x;
    int i = blockIdx.x * 256 + t;
    int v = (i < N_NODES) ? indeg[i] + 1 : 0;   // +1 self loop
    s[t] = v; __syncthreads();
    for (int off = 1; off < 256; off <<= 1) {
        int x = (t >= off) ? s[t - off] : 0;
        __syncthreads();
        s[t] += x;
        __syncthreads();
    }
    if (i < N_NODES) incl[i] = s[t];
    if (t == 255) bsum[blockIdx.x] = s[255];
}

__global__ void k_scan2(int* __restrict__ bsum, int nb) {
    __shared__ int s[256];
    int t = threadIdx.x;
    int v = (t < nb) ? bsum[t] : 0;
    s[t] = v; __syncthreads();
    for (int off = 1; off < 256; off <<= 1) {
        int x = (t >= off) ? s[t - off] : 0;
        __syncthreads();
        s[t] += x;
        __syncthreads();
    }
    if (t < nb) bsum[t] = s[t] - v;   // exclusive
}

__global__ void k_scan3(const int* __restrict__ indeg, int* __restrict__ csr,
                        const int* __restrict__ boff, int* __restrict__ pos) {
    int i = blockIdx.x * 256 + threadIdx.x;
    if (i >= N_NODES) return;
    int inc = csr[i] + boff[i >> 8];
    int ex = inc - indeg[i] - 1;
    csr[i] = ex;
    pos[i] = ex;
    if (i == N_NODES - 1) csr[N_NODES] = inc;
}

__global__ void k_scatter(const int* __restrict__ src, const int* __restrict__ dst,
                          int* __restrict__ pos, int* __restrict__ esrc) {
    int t = blockIdx.x * 256 + threadIdx.x;
    if (t < N_EDGES) {
        int d = dst[t];
        int p = atomicAdd(&pos[d], 1);
        esrc[p] = src[t];
    } else if (t < EP) {
        int n = t - N_EDGES;
        int p = atomicAdd(&pos[n], 1);
        esrc[p] = n;                  // self loop
    }
}

// ---------------- weight prep: w_als[i][j] = (W1 . a1)(head), w2v[i][j] = W2 . a2 ----------------
__global__ void k_wprep(const float* __restrict__ W1,
                        const float* __restrict__ a1s, const float* __restrict__ a1d,
                        const float* __restrict__ W2,
                        const float* __restrict__ a2s, const float* __restrict__ a2d,
                        float* __restrict__ w_als, float* __restrict__ w2v) {
    int t = threadIdx.x;
    for (int it = 0; it < 4; ++it) {
        int u = it * 256 + t;           // 1024 units
        int i = u >> 3, j = u & 7;
        int head = j & 3;
        const float* vec = (j < 4) ? a1s : a1d;
        float s = 0.f;
        for (int c = 0; c < 32; ++c)
            s += W1[i * 128 + head * 32 + c] * vec[head * 32 + c];
        w_als[u] = s;
    }
    {
        int i = t >> 1, j = t & 1;
        const float* vec = j ? a2d : a2s;
        float s = 0.f;
        for (int c = 0; c < 32; ++c)
            s += W2[i * 32 + c] * vec[c];
        w2v[i * 2 + j] = s;
    }
}

// ---------------- cvt: x -> bf16 xb, + conv1 logits (f32, via x . (W1 a)) ----------------
__global__ __launch_bounds__(256) void k_cvt(const float* __restrict__ x,
                                             const float* __restrict__ w_als,
                                             uint2* __restrict__ xb2,
                                             float* __restrict__ als1, float* __restrict__ ald1) {
    __shared__ float wc[1024];          // column-major: wc[j*128 + ch]
    int t = threadIdx.x;
    for (int u = t; u < 1024; u += 256) {
        int ch = u >> 3, j = u & 7;
        wc[j * 128 + ch] = w_als[u];
    }
    __syncthreads();
    int n = blockIdx.x * 8 + (t >> 5);
    int cp = t & 31;
    float4 xv = *(const float4*)&x[n * 128 + cp * 4];
    xb2[n * 32 + cp] = make_uint2(bfpair(xv.x, xv.y), bfpair(xv.z, xv.w));
    float p[8];
#pragma unroll
    for (int j = 0; j < 8; ++j) {
        float4 w = *(const float4*)&wc[j * 128 + cp * 4];
        p[j] = xv.x * w.x + xv.y * w.y + xv.z * w.z + xv.w * w.w;
    }
#pragma unroll
    for (int off = 1; off < 32; off <<= 1) {
#pragma unroll
        for (int j = 0; j < 8; ++j) p[j] += __shfl_xor(p[j], off);
    }
    if (cp == 0) {
        float4 s = {p[0], p[1], p[2], p[3]};
        float4 d = {p[4], p[5], p[6], p[7]};
        *(float4*)&als1[n * 4] = s;
        *(float4*)&ald1[n * 4] = d;
    }
}

// ---------------- GEMM1 (MFMA): h1b = bf16( xb @ (W1hi+W1lo) ), dword w = chs (w, w+64) ----------------
__global__ __launch_bounds__(256) void k_gemm1(const uint4* __restrict__ xb4,
                                               const float* __restrict__ W,
                                               uint* __restrict__ h1b) {
    __shared__ uint4 WH[2048];          // Wt_hi[n][k] swizzled, 32 KB
    __shared__ uint4 WL[2048];          // Wt_lo
    int t = threadIdx.x;
    uint* whw = (uint*)WH;
    uint* wlw = (uint*)WL;
    for (int it = 0; it < 16; ++it) {
        int u = it * 256 + t;
        int n = u & 127, kq = u >> 7;   // kq: 4-wide k group (0..31)
        float w0 = W[(kq * 4 + 0) * 128 + n];
        float w1 = W[(kq * 4 + 1) * 128 + n];
        float w2 = W[(kq * 4 + 2) * 128 + n];
        float w3 = W[(kq * 4 + 3) * 128 + n];
        uint h0 = bfr(w0), h1 = bfr(w1), h2 = bfr(w2), h3 = bfr(w3);
        float l0 = w0 - __uint_as_float(h0 << 16);
        float l1 = w1 - __uint_as_float(h1 << 16);
        float l2 = w2 - __uint_as_float(h2 << 16);
        float l3 = w3 - __uint_as_float(h3 << 16);
        int word = n * 64 + (((kq >> 1) ^ (n & 7)) << 2) + (kq & 1) * 2;
        *(uint2*)&whw[word] = make_uint2(h0 | (h1 << 16), h2 | (h3 << 16));
        *(uint2*)&wlw[word] = make_uint2(bfr(l0) | (bfr(l1) << 16), bfr(l2) | (bfr(l3) << 16));
    }
    __syncthreads();
    int l = t & 63, wid = t >> 6;
    int lr = l & 15, lg = l >> 4;
    int rowb = blockIdx.x * 128 + wid * 32;
    f32x4 acc[2][8] = {};
#pragma unroll
    for (int ks = 0; ks < 4; ++ks) {
        uint4 av0 = xb4[(rowb + lr) * 16 + ks * 4 + lg];
        uint4 av1 = xb4[(rowb + 16 + lr) * 16 + ks * 4 + lg];
        bf16x8 a0 = *reinterpret_cast<bf16x8*>(&av0);
        bf16x8 a1 = *reinterpret_cast<bf16x8*>(&av1);
        int quw = ks * 4 + lg;
#pragma unroll
        for (int nt = 0; nt < 8; ++nt) {
            int n = nt * 16 + lr;
            int idx = n * 16 + (quw ^ (n & 7));
            bf16x8 bh = *reinterpret_cast<bf16x8*>(&WH[idx]);
            bf16x8 bl = *reinterpret_cast<bf16x8*>(&WL[idx]);
            acc[0][nt] = __builtin_amdgcn_mfma_f32_16x16x32_bf16(a0, bh, acc[0][nt], 0, 0, 0);
            acc[0][nt] = __builtin_amdgcn_mfma_f32_16x16x32_bf16(a0, bl, acc[0][nt], 0, 0, 0);
            acc[1][nt] = __builtin_amdgcn_mfma_f32_16x16x32_bf16(a1, bh, acc[1][nt], 0, 0, 0);
            acc[1][nt] = __builtin_amdgcn_mfma_f32_16x16x32_bf16(a1, bl, acc[1][nt], 0, 0, 0);
        }
    }
#pragma unroll
    for (int mt = 0; mt < 2; ++mt)
#pragma unroll
        for (int nt = 0; nt < 4; ++nt)
#pragma unroll
            for (int r = 0; r < 4; ++r) {
                int row = rowb + mt * 16 + 4 * lg + r;
                if (row < N_NODES)
                    h1b[row * 64 + nt * 16 + lr] = bfpair(acc[mt][nt][r], acc[mt][nt + 4][r]);
            }
}

// ---------------- agg1: gather + online softmax (no max), o1b bf16 + conv2 logits ----------------
__global__ __launch_bounds__(256) void k_agg1(const uint2* __restrict__ h1b2,
                                              const int* __restrict__ csr, const int* __restrict__ esrc,
                                              const float* __restrict__ als1, const float* __restrict__ ald1,
                                              const float* __restrict__ b1,
                                              const float* __restrict__ w2v,
                                              uint* __restrict__ o1b,
                                              float* __restrict__ als2, float* __restrict__ ald2) {
    int l = threadIdx.x & 63;
    int n = blockIdx.x * 4 + (threadIdx.x >> 6);
    int s = csr[n], e = csr[n + 1];
    int cp = l & 31, half = l >> 5;
    int hh0 = cp >> 4;                     // head of lo channels; hi head = hh0+2
    float4 adv = *(const float4*)&ald1[n * 4];
    float ad0 = (cp < 16) ? adv.x : adv.y;
    float ad1 = (cp < 16) ? adv.z : adv.w;
    float acc0 = 0.f, acc1 = 0.f, acc2 = 0.f, acc3 = 0.f, ss0 = 0.f, ss1 = 0.f;
#pragma unroll 2
    for (int i = s + half; i < e; i += 2) {
        int sa = esrc[i];
        float l0 = als1[sa * 4 + hh0];
        float l1 = als1[sa * 4 + 2 + hh0];
        float e0 = __expf(lrelu(l0 + ad0));
        float e1 = __expf(lrelu(l1 + ad1));
        uint2 d = h1b2[sa * 32 + cp];
        ss0 += e0; ss1 += e1;
        acc0 += e0 * bflo(d.x); acc1 += e1 * bfhi(d.x);
        acc2 += e0 * bflo(d.y); acc3 += e1 * bfhi(d.y);
    }
    acc0 += __shfl_xor(acc0, 32); acc1 += __shfl_xor(acc1, 32);
    acc2 += __shfl_xor(acc2, 32); acc3 += __shfl_xor(acc3, 32);
    ss0  += __shfl_xor(ss0, 32);  ss1  += __shfl_xor(ss1, 32);
    if (half == 0) {
        float inv0 = 1.f / ss0, inv1 = 1.f / ss1;
        float2 bb0 = *(const float2*)&b1[2 * cp];
        float2 bb1 = *(const float2*)&b1[64 + 2 * cp];
        float v00 = eluf(acc0 * inv0 + bb0.x);   // ch 2cp
        float v01 = eluf(acc2 * inv0 + bb0.y);   // ch 2cp+1
        float v10 = eluf(acc1 * inv1 + bb1.x);   // ch 2cp+64
        float v11 = eluf(acc3 * inv1 + bb1.y);   // ch 2cp+65
        o1b[n * 64 + cp]      = bfpair(v00, v01);
        o1b[n * 64 + 32 + cp] = bfpair(v10, v11);
        const float4* w2v4 = (const float4*)w2v;
        float4 wv0 = w2v4[cp];        // [2cp][0..1],[2cp+1][0..1]
        float4 wv1 = w2v4[32 + cp];   // [2cp+64][0..1],[2cp+65][0..1]
        float p0 = v00 * wv0.x + v01 * wv0.z + v10 * wv1.x + v11 * wv1.z;
        float p1 = v00 * wv0.y + v01 * wv0.w + v10 * wv1.y + v11 * wv1.w;
#pragma unroll
        for (int off = 1; off < 32; off <<= 1) {
            p0 += __shfl_xor(p0, off);
            p1 += __shfl_xor(p1, off);
        }
        if (cp == 0) { als2[n] = p0; ald2[n] = p1; }
    }
}

// ---------------- GEMM2 (MFMA): h2b = bf16( o1b @ (W2hi+W2lo) ), dword w = chs (w, w+16) ----------------
__global__ __launch_bounds__(256) void k_gemm2(const uint4* __restrict__ ob4,
                                               const float* __restrict__ W,
                                               uint* __restrict__ h2b) {
    __shared__ uint4 WH[512];           // Wt_hi[n 0..31][k] swizzled, 8 KB
    __shared__ uint4 WL[512];
    int t = threadIdx.x;
    uint* whw = (uint*)WH;
    uint* wlw = (uint*)WL;
    for (int it = 0; it < 4; ++it) {
        int u = it * 256 + t;
        int n = u & 31, kq = u >> 5;
        float w0 = W[(kq * 4 + 0) * 32 + n];
        float w1 = W[(kq * 4 + 1) * 32 + n];
        float w2 = W[(kq * 4 + 2) * 32 + n];
        float w3 = W[(kq * 4 + 3) * 32 + n];
        uint h0 = bfr(w0), h1 = bfr(w1), h2 = bfr(w2), h3 = bfr(w3);
        float l0 = w0 - __uint_as_float(h0 << 16);
        float l1 = w1 - __uint_as_float(h1 << 16);
        float l2 = w2 - __uint_as_float(h2 << 16);
        float l3 = w3 - __uint_as_float(h3 << 16);
        int word = n * 64 + (((kq >> 1) ^ (n & 7)) << 2) + (kq & 1) * 2;
        *(uint2*)&whw[word] = make_uint2(h0 | (h1 << 16), h2 | (h3 << 16));
        *(uint2*)&wlw[word] = make_uint2(bfr(l0) | (bfr(l1) << 16), bfr(l2) | (bfr(l3) << 16));
    }
    __syncthreads();
    int l = t & 63, wid = t >> 6;
    int lr = l & 15, lg = l >> 4;
    int rowb = blockIdx.x * 128 + wid * 32;
    f32x4 acc[2][2] = {};
#pragma unroll
    for (int ks = 0; ks < 4; ++ks) {
        uint4 av0 = ob4[(rowb + lr) * 16 + ks * 4 + lg];
        uint4 av1 = ob4[(rowb + 16 + lr) * 16 + ks * 4 + lg];
        bf16x8 a0 = *reinterpret_cast<bf16x8*>(&av0);
        bf16x8 a1 = *reinterpret_cast<bf16x8*>(&av1);
        int quw = ks * 4 + lg;
#pragma unroll
        for (int nt = 0; nt < 2; ++nt) {
            int n = nt * 16 + lr;
            int idx = n * 16 + (quw ^ (n & 7));
            bf16x8 bh = *reinterpret_cast<bf16x8*>(&WH[idx]);
            bf16x8 bl = *reinterpret_cast<bf16x8*>(&WL[idx]);
            acc[0][nt] = __builtin_amdgcn_mfma_f32_16x16x32_bf16(a0, bh, acc[0][nt], 0, 0, 0);
            acc[0][nt] = __builtin_amdgcn_mfma_f32_16x16x32_bf16(a0, bl, acc[0][nt], 0, 0, 0);
            acc[1][nt] = __builtin_amdgcn_mfma_f32_16x16x32_bf16(a1, bh, acc[1][nt], 0, 0, 0);
            acc[1][nt] = __builtin_amdgcn_mfma_f32_16x16x32_bf16(a1, bl, acc[1][nt], 0, 0, 0);
        }
    }
#pragma unroll
    for (int mt = 0; mt < 2; ++mt)
#pragma unroll
        for (int r = 0; r < 4; ++r) {
            int row = rowb + mt * 16 + 4 * lg + r;
            if (row < N_NODES)
                h2b[row * 16 + lr] = bfpair(acc[mt][0][r], acc[mt][1][r]);
        }
}

// ---------------- agg2: single pass, quarter-wave per edge ----------------
__global__ __launch_bounds__(256) void k_agg2(const uint* __restrict__ h2b,
                                              const int* __restrict__ csr, const int* __restrict__ esrc,
                                              const float* __restrict__ als, const float* __restrict__ ald,
                                              const float* __restrict__ b2,
                                              float* __restrict__ o2) {
    int l = threadIdx.x & 63;
    int n = blockIdx.x * 4 + (threadIdx.x >> 6);
    int s = csr[n], e = csr[n + 1];
    int cp = l & 15, sub = l >> 4;    // 4 edges in flight
    float ad = ald[n];
    float acc0 = 0.f, acc1 = 0.f, ssum = 0.f;
#pragma unroll 2
    for (int i = s + sub; i < e; i += 4) {
        int sa = esrc[i];
        float ex = __expf(lrelu(als[sa] + ad));
        ssum += ex;
        uint d = h2b[sa * 16 + cp];
        acc0 += ex * bflo(d); acc1 += ex * bfhi(d);
    }
    acc0 += __shfl_xor(acc0, 16); acc1 += __shfl_xor(acc1, 16); ssum += __shfl_xor(ssum, 16);
    acc0 += __shfl_xor(acc0, 32); acc1 += __shfl_xor(acc1, 32); ssum += __shfl_xor(ssum, 32);
    if (l < 16) {
        float inv = 1.f / ssum;
        o2[n * 32 + cp]      = eluf(acc0 * inv + b2[cp]);        // ch cp
        o2[n * 32 + 16 + cp] = eluf(acc1 * inv + b2[16 + cp]);   // ch cp+16
    }
}

// ---------------- fused pool + final linear (inline boundary search) ----------------
__global__ __launch_bounds__(256) void k_poolfinal(const float* __restrict__ out2,
                                                   const int* __restrict__ batch,
                                                   const float* __restrict__ Wl,
                                                   const float* __restrict__ bl,
                                                   float* __restrict__ out) {
    __shared__ float red[4][32];
    __shared__ float pooled[32];
    int g = blockIdx.x;
    int s = 0, hi = N_NODES;
    while (s < hi) { int mid = (s + hi) >> 1; if (batch[mid] < g) s = mid + 1; else hi = mid; }
    int e = s; hi = N_NODES;
    while (e < hi) { int mid = (e + hi) >> 1; if (batch[mid] < g + 1) e = mid + 1; else hi = mid; }
    int t = threadIdx.x;
    int c = t & 31, r = t >> 5;
    float acc = 0.f;
    for (int i = s + r; i < e; i += 8)
        acc += out2[i * 32 + c];
    acc += __shfl_xor(acc, 32);
    if ((t & 63) < 32) red[t >> 6][c] = acc;
    __syncthreads();
    if (t < 32) {
        float v = red[0][t] + red[1][t] + red[2][t] + red[3][t];
        float cnt = fmaxf((float)(e - s), 1.f);
        pooled[t] = v / cnt;
    }
    __syncthreads();
    if (t < OUTC) {
        float a = 0.f;
        for (int cc = 0; cc < HIDC; cc++)
            a += pooled[cc] * Wl[cc * OUTC + t];
        out[g * OUTC + t] = a + bl[t];
    }
}

extern "C" void kernel_launch(void* const* d_in, const int* in_sizes, int n_in,
                              void* d_out, int out_size, void* d_ws, size_t ws_size,
                              hipStream_t stream) {
    (void)in_sizes; (void)n_in; (void)out_size; (void)ws_size;
    const float* x    = (const float*)d_in[0];
    const int*   ei   = (const int*)d_in[1];
    const int*   srcA = ei;
    const int*   dstA = ei + N_EDGES;
    const int*   batch = (const int*)d_in[2];
    const float* W1  = (const float*)d_in[3];
    const float* a1s = (const float*)d_in[4];
    const float* a1d = (const float*)d_in[5];
    const float* b1  = (const float*)d_in[6];
    const float* W2  = (const float*)d_in[7];
    const float* a2s = (const float*)d_in[8];
    const float* a2d = (const float*)d_in[9];
    const float* b2  = (const float*)d_in[10];
    const float* Wl  = (const float*)d_in[11];
    const float* bl  = (const float*)d_in[12];
    float* out = (float*)d_out;

    char* w = (char*)d_ws;
    auto alloc = [&](size_t bytes) -> void* {
        void* p = (void*)w;
        w += (bytes + 255) & ~(size_t)255;
        return p;
    };
    uint*  xb   = (uint*)alloc((size_t)NPAD * 64 * 4);       // x bf16, 12.85 MB
    uint*  h1b  = (uint*)alloc((size_t)N_NODES * 64 * 4);    // 12.8 MB
    uint*  o1b  = (uint*)alloc((size_t)NPAD * 64 * 4);       // 12.85 MB
    uint*  h2b  = (uint*)alloc((size_t)N_NODES * 16 * 4);    // 3.2 MB
    float* o2   = (float*)alloc((size_t)N_NODES * 32 * 4);   // 6.4 MB
    float* als1 = (float*)alloc((size_t)N_NODES * 4 * 4);
    float* ald1 = (float*)alloc((size_t)N_NODES * 4 * 4);
    float* als2 = (float*)alloc((size_t)N_NODES * 4);
    float* ald2 = (float*)alloc((size_t)N_NODES * 4);
    float* w_als = (float*)alloc(1024 * 4);
    float* w2v   = (float*)alloc(256 * 4);
    int*   indeg = (int*)alloc((size_t)N_NODES * 4);
    int*   csr   = (int*)alloc((size_t)(N_NODES + 1) * 4);
    int*   pos   = (int*)alloc((size_t)N_NODES * 4);
    int*   esrc  = (int*)alloc((size_t)EP * 4);
    int*   bsum  = (int*)alloc(256 * 4);

    int nb = (N_NODES + 255) / 256;   // 196

    hipMemsetAsync(indeg, 0, (size_t)N_NODES * 4, stream);
    k_count<<<(N_EDGES + 255) / 256, 256, 0, stream>>>(dstA, indeg);
    k_scan1<<<nb, 256, 0, stream>>>(indeg, csr, bsum);
    k_scan2<<<1, 256, 0, stream>>>(bsum, nb);
    k_scan3<<<nb, 256, 0, stream>>>(indeg, csr, bsum, pos);
    k_scatter<<<(EP + 255) / 256, 256, 0, stream>>>(srcA, dstA, pos, esrc);
    k_wprep<<<1, 256, 0, stream>>>(W1, a1s, a1d, W2, a2s, a2d, w_als, w2v);
    k_cvt<<<N_NODES / 8, 256, 0, stream>>>(x, w_als, (uint2*)xb, als1, ald1);
    k_gemm1<<<NPAD / 128, 256, 0, stream>>>((const uint4*)xb, W1, h1b);
    k_agg1<<<N_NODES / 4, 256, 0, stream>>>((const uint2*)h1b, csr, esrc, als1, ald1, b1, w2v,
                                            o1b, als2, ald2);
    k_gemm2<<<NPAD / 128, 256, 0, stream>>>((const uint4*)o1b, W2, h2b);
    k_agg2<<<N_NODES / 4, 256, 0, stream>>>(h2b, csr, esrc, als2, ald2, b2, o2);
    k_poolfinal<<<NGRAPH, 256, 0, stream>>>(o2, batch, Wl, bl, out);
}

// Round 6
// 242.157 us; speedup vs baseline: 3.1119x; 1.0340x over previous
//
#include <hip/hip_runtime.h>
#include <math.h>

#define N_NODES 50000
#define N_EDGES 800000
#define EP      (N_EDGES + N_NODES)   // edges incl. self loops
#define IN_CH   128
#define HIDC    32
#define HEADS   4
#define OUTC    10
#define NGRAPH  64
#define NEG_SLOPE 0.2f
#define NPAD    50176                  // 128-row padded node count
#define NPART   8
#define PRNG    (N_NODES / NPART)      // 6250 nodes per partition

typedef unsigned int uint;
typedef __attribute__((ext_vector_type(8))) short bf16x8;
typedef __attribute__((ext_vector_type(4))) float f32x4;

__device__ __forceinline__ float lrelu(float x) { return x > 0.f ? x : NEG_SLOPE * x; }
__device__ __forceinline__ float eluf(float x)  { return x > 0.f ? x : __expf(x) - 1.f; }

__device__ __forceinline__ uint bfr(float f) {                 // f32 -> bf16 bits (RNE)
    uint a = __float_as_uint(f);
    return (a + 0x7FFFu + ((a >> 16) & 1u)) >> 16;
}
__device__ __forceinline__ uint bfpair(float lo, float hi) { return bfr(lo) | (bfr(hi) << 16); }
__device__ __forceinline__ float bflo(uint d) { return __uint_as_float(d << 16); }
__device__ __forceinline__ float bfhi(uint d) { return __uint_as_float(d & 0xFFFF0000u); }

// ---------------- CSR build (dst-range partitioned: blockIdx%8 ~ XCD) ----------------
// Each partition scans the whole edge stream (L3-absorbed) but only touches
// indeg/pos/esrc for its own 6250-node dst range -> XCD-local atomics & writes.
__global__ __launch_bounds__(256) void k_count(const int* __restrict__ dst, int* __restrict__ indeg) {
    int part = blockIdx.x & (NPART - 1);
    int base = (blockIdx.x >> 3) * 2048;
    int lo = part * PRNG;
#pragma unroll
    for (int it = 0; it < 8; ++it) {
        int e = base + it * 256 + threadIdx.x;
        if (e < N_EDGES) {
            int d = dst[e];
            if ((uint)(d - lo) < PRNG) atomicAdd(&indeg[d], 1);
        }
    }
}

__global__ void k_scan1(const int* __restrict__ indeg, int* __restrict__ incl, int* __restrict__ bsum) {
    __shared__ int s[256];
    int t = threadIdx.x;
    int i = blockIdx.x * 256 + t;
    int v = (i < N_NODES) ? indeg[i] + 1 : 0;   // +1 self loop
    s[t] = v; __syncthreads();
    for (int off = 1; off < 256; off <<= 1) {
        int x = (t >= off) ? s[t - off] : 0;
        __syncthreads();
        s[t] += x;
        __syncthreads();
    }
    if (i < N_NODES) incl[i] = s[t];
    if (t == 255) bsum[blockIdx.x] = s[255];
}

__global__ void k_scan2(int* __restrict__ bsum, int nb) {
    __shared__ int s[256];
    int t = threadIdx.x;
    int v = (t < nb) ? bsum[t] : 0;
    s[t] = v; __syncthreads();
    for (int off = 1; off < 256; off <<= 1) {
        int x = (t >= off) ? s[t - off] : 0;
        __syncthreads();
        s[t] += x;
        __syncthreads();
    }
    if (t < nb) bsum[t] = s[t] - v;   // exclusive
}

__global__ void k_scan3(const int* __restrict__ indeg, int* __restrict__ csr,
                        const int* __restrict__ boff, int* __restrict__ pos) {
    int i = blockIdx.x * 256 + threadIdx.x;
    if (i >= N_NODES) return;
    int inc = csr[i] + boff[i >> 8];
    int ex = inc - indeg[i] - 1;
    csr[i] = ex;
    pos[i] = ex;
    if (i == N_NODES - 1) csr[N_NODES] = inc;
}

__global__ __launch_bounds__(256) void k_scatter(const int* __restrict__ src, const int* __restrict__ dst,
                                                 int* __restrict__ pos, int* __restrict__ esrc) {
    int part = blockIdx.x & (NPART - 1);
    int base = (blockIdx.x >> 3) * 2048;
    int lo = part * PRNG;
#pragma unroll
    for (int it = 0; it < 8; ++it) {
        int e = base + it * 256 + threadIdx.x;
        if (e < EP) {
            int d = (e < N_EDGES) ? dst[e] : (e - N_EDGES);
            if ((uint)(d - lo) < PRNG) {
                int s = (e < N_EDGES) ? src[e] : d;
                int p = atomicAdd(&pos[d], 1);
                esrc[p] = s;
            }
        }
    }
}

// ---------------- weight prep: w_als[i][j] = (W1 . a1)(head), w2v[i][j] = W2 . a2 ----------------
__global__ void k_wprep(const float* __restrict__ W1,
                        const float* __restrict__ a1s, const float* __restrict__ a1d,
                        const float* __restrict__ W2,
                        const float* __restrict__ a2s, const float* __restrict__ a2d,
                        float* __restrict__ w_als, float* __restrict__ w2v) {
    int t = threadIdx.x;
    for (int it = 0; it < 4; ++it) {
        int u = it * 256 + t;           // 1024 units
        int i = u >> 3, j = u & 7;
        int head = j & 3;
        const float* vec = (j < 4) ? a1s : a1d;
        float s = 0.f;
        for (int c = 0; c < 32; ++c)
            s += W1[i * 128 + head * 32 + c] * vec[head * 32 + c];
        w_als[u] = s;
    }
    {
        int i = t >> 1, j = t & 1;
        const float* vec = j ? a2d : a2s;
        float s = 0.f;
        for (int c = 0; c < 32; ++c)
            s += W2[i * 32 + c] * vec[c];
        w2v[i * 2 + j] = s;
    }
}

// ---------------- cvt: x -> bf16 xb, + conv1 logits (f32, via x . (W1 a)) ----------------
__global__ __launch_bounds__(256) void k_cvt(const float* __restrict__ x,
                                             const float* __restrict__ w_als,
                                             uint2* __restrict__ xb2,
                                             float* __restrict__ als1, float* __restrict__ ald1) {
    __shared__ float wc[1024];          // column-major: wc[j*128 + ch]
    int t = threadIdx.x;
    for (int u = t; u < 1024; u += 256) {
        int ch = u >> 3, j = u & 7;
        wc[j * 128 + ch] = w_als[u];
    }
    __syncthreads();
    int n = blockIdx.x * 8 + (t >> 5);
    int cp = t & 31;
    float4 xv = *(const float4*)&x[n * 128 + cp * 4];
    xb2[n * 32 + cp] = make_uint2(bfpair(xv.x, xv.y), bfpair(xv.z, xv.w));
    float p[8];
#pragma unroll
    for (int j = 0; j < 8; ++j) {
        float4 w = *(const float4*)&wc[j * 128 + cp * 4];
        p[j] = xv.x * w.x + xv.y * w.y + xv.z * w.z + xv.w * w.w;
    }
#pragma unroll
    for (int off = 1; off < 32; off <<= 1) {
#pragma unroll
        for (int j = 0; j < 8; ++j) p[j] += __shfl_xor(p[j], off);
    }
    if (cp == 0) {
        float4 s = {p[0], p[1], p[2], p[3]};
        float4 d = {p[4], p[5], p[6], p[7]};
        *(float4*)&als1[n * 4] = s;
        *(float4*)&ald1[n * 4] = d;
    }
}

// ---------------- GEMM1 (MFMA): h1b = bf16( xb @ (W1hi+W1lo) ), dword w = chs (w, w+64) ----------------
__global__ __launch_bounds__(256) void k_gemm1(const uint4* __restrict__ xb4,
                                               const float* __restrict__ W,
                                               uint* __restrict__ h1b) {
    __shared__ uint4 WH[2048];          // Wt_hi[n][k] swizzled, 32 KB
    __shared__ uint4 WL[2048];          // Wt_lo
    int t = threadIdx.x;
    uint* whw = (uint*)WH;
    uint* wlw = (uint*)WL;
    for (int it = 0; it < 16; ++it) {
        int u = it * 256 + t;
        int n = u & 127, kq = u >> 7;   // kq: 4-wide k group (0..31)
        float w0 = W[(kq * 4 + 0) * 128 + n];
        float w1 = W[(kq * 4 + 1) * 128 + n];
        float w2 = W[(kq * 4 + 2) * 128 + n];
        float w3 = W[(kq * 4 + 3) * 128 + n];
        uint h0 = bfr(w0), h1 = bfr(w1), h2 = bfr(w2), h3 = bfr(w3);
        float l0 = w0 - __uint_as_float(h0 << 16);
        float l1 = w1 - __uint_as_float(h1 << 16);
        float l2 = w2 - __uint_as_float(h2 << 16);
        float l3 = w3 - __uint_as_float(h3 << 16);
        int word = n * 64 + (((kq >> 1) ^ (n & 7)) << 2) + (kq & 1) * 2;
        *(uint2*)&whw[word] = make_uint2(h0 | (h1 << 16), h2 | (h3 << 16));
        *(uint2*)&wlw[word] = make_uint2(bfr(l0) | (bfr(l1) << 16), bfr(l2) | (bfr(l3) << 16));
    }
    __syncthreads();
    int l = t & 63, wid = t >> 6;
    int lr = l & 15, lg = l >> 4;
    int rowb = blockIdx.x * 128 + wid * 32;
    f32x4 acc[2][8] = {};
#pragma unroll
    for (int ks = 0; ks < 4; ++ks) {
        uint4 av0 = xb4[(rowb + lr) * 16 + ks * 4 + lg];
        uint4 av1 = xb4[(rowb + 16 + lr) * 16 + ks * 4 + lg];
        bf16x8 a0 = *reinterpret_cast<bf16x8*>(&av0);
        bf16x8 a1 = *reinterpret_cast<bf16x8*>(&av1);
        int quw = ks * 4 + lg;
#pragma unroll
        for (int nt = 0; nt < 8; ++nt) {
            int n = nt * 16 + lr;
            int idx = n * 16 + (quw ^ (n & 7));
            bf16x8 bh = *reinterpret_cast<bf16x8*>(&WH[idx]);
            bf16x8 bl = *reinterpret_cast<bf16x8*>(&WL[idx]);
            acc[0][nt] = __builtin_amdgcn_mfma_f32_16x16x32_bf16(a0, bh, acc[0][nt], 0, 0, 0);
            acc[0][nt] = __builtin_amdgcn_mfma_f32_16x16x32_bf16(a0, bl, acc[0][nt], 0, 0, 0);
            acc[1][nt] = __builtin_amdgcn_mfma_f32_16x16x32_bf16(a1, bh, acc[1][nt], 0, 0, 0);
            acc[1][nt] = __builtin_amdgcn_mfma_f32_16x16x32_bf16(a1, bl, acc[1][nt], 0, 0, 0);
        }
    }
#pragma unroll
    for (int mt = 0; mt < 2; ++mt)
#pragma unroll
        for (int nt = 0; nt < 4; ++nt)
#pragma unroll
            for (int r = 0; r < 4; ++r) {
                int row = rowb + mt * 16 + 4 * lg + r;
                if (row < N_NODES)
                    h1b[row * 64 + nt * 16 + lr] = bfpair(acc[mt][nt][r], acc[mt][nt + 4][r]);
            }
}

// ---------------- agg1: gather + single-pass softmax, o1b bf16 + conv2 logits ----------------
__global__ __launch_bounds__(256) void k_agg1(const uint2* __restrict__ h1b2,
                                              const int* __restrict__ csr, const int* __restrict__ esrc,
                                              const float* __restrict__ als1, const float* __restrict__ ald1,
                                              const float* __restrict__ b1,
                                              const float* __restrict__ w2v,
                                              uint* __restrict__ o1b,
                                              float* __restrict__ als2, float* __restrict__ ald2) {
    int l = threadIdx.x & 63;
    int n = blockIdx.x * 4 + (threadIdx.x >> 6);
    int s = csr[n], e = csr[n + 1];
    int cp = l & 31, half = l >> 5;
    int hh0 = cp >> 4;                     // head of lo channels; hi head = hh0+2
    float4 adv = *(const float4*)&ald1[n * 4];
    float ad0 = (cp < 16) ? adv.x : adv.y;
    float ad1 = (cp < 16) ? adv.z : adv.w;
    float acc0 = 0.f, acc1 = 0.f, acc2 = 0.f, acc3 = 0.f, ss0 = 0.f, ss1 = 0.f;
#pragma unroll 2
    for (int i = s + half; i < e; i += 2) {
        int sa = esrc[i];
        float l0 = als1[sa * 4 + hh0];
        float l1 = als1[sa * 4 + 2 + hh0];
        float e0 = __expf(lrelu(l0 + ad0));
        float e1 = __expf(lrelu(l1 + ad1));
        uint2 d = h1b2[sa * 32 + cp];
        ss0 += e0; ss1 += e1;
        acc0 += e0 * bflo(d.x); acc1 += e1 * bfhi(d.x);
        acc2 += e0 * bflo(d.y); acc3 += e1 * bfhi(d.y);
    }
    acc0 += __shfl_xor(acc0, 32); acc1 += __shfl_xor(acc1, 32);
    acc2 += __shfl_xor(acc2, 32); acc3 += __shfl_xor(acc3, 32);
    ss0  += __shfl_xor(ss0, 32);  ss1  += __shfl_xor(ss1, 32);
    if (half == 0) {
        float inv0 = 1.f / ss0, inv1 = 1.f / ss1;
        float2 bb0 = *(const float2*)&b1[2 * cp];
        float2 bb1 = *(const float2*)&b1[64 + 2 * cp];
        float v00 = eluf(acc0 * inv0 + bb0.x);   // ch 2cp
        float v01 = eluf(acc2 * inv0 + bb0.y);   // ch 2cp+1
        float v10 = eluf(acc1 * inv1 + bb1.x);   // ch 2cp+64
        float v11 = eluf(acc3 * inv1 + bb1.y);   // ch 2cp+65
        o1b[n * 64 + cp]      = bfpair(v00, v01);
        o1b[n * 64 + 32 + cp] = bfpair(v10, v11);
        const float4* w2v4 = (const float4*)w2v;
        float4 wv0 = w2v4[cp];        // [2cp][0..1],[2cp+1][0..1]
        float4 wv1 = w2v4[32 + cp];   // [2cp+64][0..1],[2cp+65][0..1]
        float p0 = v00 * wv0.x + v01 * wv0.z + v10 * wv1.x + v11 * wv1.z;
        float p1 = v00 * wv0.y + v01 * wv0.w + v10 * wv1.y + v11 * wv1.w;
#pragma unroll
        for (int off = 1; off < 32; off <<= 1) {
            p0 += __shfl_xor(p0, off);
            p1 += __shfl_xor(p1, off);
        }
        if (cp == 0) { als2[n] = p0; ald2[n] = p1; }
    }
}

// ---------------- GEMM2 (MFMA): h2b = bf16( o1b @ (W2hi+W2lo) ), dword w = chs (w, w+16) ----------------
__global__ __launch_bounds__(256) void k_gemm2(const uint4* __restrict__ ob4,
                                               const float* __restrict__ W,
                                               uint* __restrict__ h2b) {
    __shared__ uint4 WH[512];           // Wt_hi[n 0..31][k] swizzled, 8 KB
    __shared__ uint4 WL[512];
    int t = threadIdx.x;
    uint* whw = (uint*)WH;
    uint* wlw = (uint*)WL;
    for (int it = 0; it < 4; ++it) {
        int u = it * 256 + t;
        int n = u & 31, kq = u >> 5;
        float w0 = W[(kq * 4 + 0) * 32 + n];
        float w1 = W[(kq * 4 + 1) * 32 + n];
        float w2 = W[(kq * 4 + 2) * 32 + n];
        float w3 = W[(kq * 4 + 3) * 32 + n];
        uint h0 = bfr(w0), h1 = bfr(w1), h2 = bfr(w2), h3 = bfr(w3);
        float l0 = w0 - __uint_as_float(h0 << 16);
        float l1 = w1 - __uint_as_float(h1 << 16);
        float l2 = w2 - __uint_as_float(h2 << 16);
        float l3 = w3 - __uint_as_float(h3 << 16);
        int word = n * 64 + (((kq >> 1) ^ (n & 7)) << 2) + (kq & 1) * 2;
        *(uint2*)&whw[word] = make_uint2(h0 | (h1 << 16), h2 | (h3 << 16));
        *(uint2*)&wlw[word] = make_uint2(bfr(l0) | (bfr(l1) << 16), bfr(l2) | (bfr(l3) << 16));
    }
    __syncthreads();
    int l = t & 63, wid = t >> 6;
    int lr = l & 15, lg = l >> 4;
    int rowb = blockIdx.x * 128 + wid * 32;
    f32x4 acc[2][2] = {};
#pragma unroll
    for (int ks = 0; ks < 4; ++ks) {
        uint4 av0 = ob4[(rowb + lr) * 16 + ks * 4 + lg];
        uint4 av1 = ob4[(rowb + 16 + lr) * 16 + ks * 4 + lg];
        bf16x8 a0 = *reinterpret_cast<bf16x8*>(&av0);
        bf16x8 a1 = *reinterpret_cast<bf16x8*>(&av1);
        int quw = ks * 4 + lg;
#pragma unroll
        for (int nt = 0; nt < 2; ++nt) {
            int n = nt * 16 + lr;
            int idx = n * 16 + (quw ^ (n & 7));
            bf16x8 bh = *reinterpret_cast<bf16x8*>(&WH[idx]);
            bf16x8 bl = *reinterpret_cast<bf16x8*>(&WL[idx]);
            acc[0][nt] = __builtin_amdgcn_mfma_f32_16x16x32_bf16(a0, bh, acc[0][nt], 0, 0, 0);
            acc[0][nt] = __builtin_amdgcn_mfma_f32_16x16x32_bf16(a0, bl, acc[0][nt], 0, 0, 0);
            acc[1][nt] = __builtin_amdgcn_mfma_f32_16x16x32_bf16(a1, bh, acc[1][nt], 0, 0, 0);
            acc[1][nt] = __builtin_amdgcn_mfma_f32_16x16x32_bf16(a1, bl, acc[1][nt], 0, 0, 0);
        }
    }
#pragma unroll
    for (int mt = 0; mt < 2; ++mt)
#pragma unroll
        for (int r = 0; r < 4; ++r) {
            int row = rowb + mt * 16 + 4 * lg + r;
            if (row < N_NODES)
                h2b[row * 16 + lr] = bfpair(acc[mt][0][r], acc[mt][1][r]);
        }
}

// ---------------- agg2: single pass, quarter-wave per edge ----------------
__global__ __launch_bounds__(256) void k_agg2(const uint* __restrict__ h2b,
                                              const int* __restrict__ csr, const int* __restrict__ esrc,
                                              const float* __restrict__ als, const float* __restrict__ ald,
                                              const float* __restrict__ b2,
                                              float* __restrict__ o2) {
    int l = threadIdx.x & 63;
    int n = blockIdx.x * 4 + (threadIdx.x >> 6);
    int s = csr[n], e = csr[n + 1];
    int cp = l & 15, sub = l >> 4;    // 4 edges in flight
    float ad = ald[n];
    float acc0 = 0.f, acc1 = 0.f, ssum = 0.f;
#pragma unroll 2
    for (int i = s + sub; i < e; i += 4) {
        int sa = esrc[i];
        float ex = __expf(lrelu(als[sa] + ad));
        ssum += ex;
        uint d = h2b[sa * 16 + cp];
        acc0 += ex * bflo(d); acc1 += ex * bfhi(d);
    }
    acc0 += __shfl_xor(acc0, 16); acc1 += __shfl_xor(acc1, 16); ssum += __shfl_xor(ssum, 16);
    acc0 += __shfl_xor(acc0, 32); acc1 += __shfl_xor(acc1, 32); ssum += __shfl_xor(ssum, 32);
    if (l < 16) {
        float inv = 1.f / ssum;
        o2[n * 32 + cp]      = eluf(acc0 * inv + b2[cp]);        // ch cp
        o2[n * 32 + 16 + cp] = eluf(acc1 * inv + b2[16 + cp]);   // ch cp+16
    }
}

// ---------------- fused pool + final linear (inline boundary search) ----------------
__global__ __launch_bounds__(256) void k_poolfinal(const float* __restrict__ out2,
                                                   const int* __restrict__ batch,
                                                   const float* __restrict__ Wl,
                                                   const float* __restrict__ bl,
                                                   float* __restrict__ out) {
    __shared__ float red[4][32];
    __shared__ float pooled[32];
    int g = blockIdx.x;
    int s = 0, hi = N_NODES;
    while (s < hi) { int mid = (s + hi) >> 1; if (batch[mid] < g) s = mid + 1; else hi = mid; }
    int e = s; hi = N_NODES;
    while (e < hi) { int mid = (e + hi) >> 1; if (batch[mid] < g + 1) e = mid + 1; else hi = mid; }
    int t = threadIdx.x;
    int c = t & 31, r = t >> 5;
    float acc = 0.f;
    for (int i = s + r; i < e; i += 8)
        acc += out2[i * 32 + c];
    acc += __shfl_xor(acc, 32);
    if ((t & 63) < 32) red[t >> 6][c] = acc;
    __syncthreads();
    if (t < 32) {
        float v = red[0][t] + red[1][t] + red[2][t] + red[3][t];
        float cnt = fmaxf((float)(e - s), 1.f);
        pooled[t] = v / cnt;
    }
    __syncthreads();
    if (t < OUTC) {
        float a = 0.f;
        for (int cc = 0; cc < HIDC; cc++)
            a += pooled[cc] * Wl[cc * OUTC + t];
        out[g * OUTC + t] = a + bl[t];
    }
}

extern "C" void kernel_launch(void* const* d_in, const int* in_sizes, int n_in,
                              void* d_out, int out_size, void* d_ws, size_t ws_size,
                              hipStream_t stream) {
    (void)in_sizes; (void)n_in; (void)out_size; (void)ws_size;
    const float* x    = (const float*)d_in[0];
    const int*   ei   = (const int*)d_in[1];
    const int*   srcA = ei;
    const int*   dstA = ei + N_EDGES;
    const int*   batch = (const int*)d_in[2];
    const float* W1  = (const float*)d_in[3];
    const float* a1s = (const float*)d_in[4];
    const float* a1d = (const float*)d_in[5];
    const float* b1  = (const float*)d_in[6];
    const float* W2  = (const float*)d_in[7];
    const float* a2s = (const float*)d_in[8];
    const float* a2d = (const float*)d_in[9];
    const float* b2  = (const float*)d_in[10];
    const float* Wl  = (const float*)d_in[11];
    const float* bl  = (const float*)d_in[12];
    float* out = (float*)d_out;

    char* w = (char*)d_ws;
    auto alloc = [&](size_t bytes) -> void* {
        void* p = (void*)w;
        w += (bytes + 255) & ~(size_t)255;
        return p;
    };
    uint*  xb   = (uint*)alloc((size_t)NPAD * 64 * 4);       // x bf16, 12.85 MB
    uint*  h1b  = (uint*)alloc((size_t)N_NODES * 64 * 4);    // 12.8 MB
    uint*  o1b  = (uint*)alloc((size_t)NPAD * 64 * 4);       // 12.85 MB
    uint*  h2b  = (uint*)alloc((size_t)N_NODES * 16 * 4);    // 3.2 MB
    float* o2   = (float*)alloc((size_t)N_NODES * 32 * 4);   // 6.4 MB
    float* als1 = (float*)alloc((size_t)N_NODES * 4 * 4);
    float* ald1 = (float*)alloc((size_t)N_NODES * 4 * 4);
    float* als2 = (float*)alloc((size_t)N_NODES * 4);
    float* ald2 = (float*)alloc((size_t)N_NODES * 4);
    float* w_als = (float*)alloc(1024 * 4);
    float* w2v   = (float*)alloc(256 * 4);
    int*   indeg = (int*)alloc((size_t)N_NODES * 4);
    int*   csr   = (int*)alloc((size_t)(N_NODES + 1) * 4);
    int*   pos   = (int*)alloc((size_t)N_NODES * 4);
    int*   esrc  = (int*)alloc((size_t)EP * 4);
    int*   bsum  = (int*)alloc(256 * 4);

    int nb = (N_NODES + 255) / 256;   // 196
    int ncc = (N_EDGES + 2047) / 2048;   // count chunks: 391
    int nsc = (EP + 2047) / 2048;        // scatter chunks: 416

    hipMemsetAsync(indeg, 0, (size_t)N_NODES * 4, stream);
    k_count<<<ncc * NPART, 256, 0, stream>>>(dstA, indeg);
    k_scan1<<<nb, 256, 0, stream>>>(indeg, csr, bsum);
    k_scan2<<<1, 256, 0, stream>>>(bsum, nb);
    k_scan3<<<nb, 256, 0, stream>>>(indeg, csr, bsum, pos);
    k_scatter<<<nsc * NPART, 256, 0, stream>>>(srcA, dstA, pos, esrc);
    k_wprep<<<1, 256, 0, stream>>>(W1, a1s, a1d, W2, a2s, a2d, w_als, w2v);
    k_cvt<<<N_NODES / 8, 256, 0, stream>>>(x, w_als, (uint2*)xb, als1, ald1);
    k_gemm1<<<NPAD / 128, 256, 0, stream>>>((const uint4*)xb, W1, h1b);
    k_agg1<<<N_NODES / 4, 256, 0, stream>>>((const uint2*)h1b, csr, esrc, als1, ald1, b1, w2v,
                                            o1b, als2, ald2);
    k_gemm2<<<NPAD / 128, 256, 0, stream>>>((const uint4*)o1b, W2, h2b);
    k_agg2<<<N_NODES / 4, 256, 0, stream>>>(h2b, csr, esrc, als2, ald2, b2, o2);
    k_poolfinal<<<NGRAPH, 256, 0, stream>>>(o2, batch, Wl, bl, out);
}